// Round 10
// baseline (2270.803 us; speedup 1.0000x reference)
//
#include <hip/hip_runtime.h>
#include <hip/hip_bf16.h>
#include <math.h>

#define LEN 65536
#define LOUT 64536
typedef __hip_bfloat16 bf16;
typedef __attribute__((ext_vector_type(8))) short short8;
typedef __attribute__((ext_vector_type(4))) float f32x4;

__device__ inline float b2f(bf16 h) { return __bfloat162float(h); }
__device__ inline bf16 f2b(float f) { return __float2bfloat16(f); }
__device__ inline float us2f(unsigned short u) { bf16 h = *(bf16*)&u; return __bfloat162float(h); }
// cheap softplus: max(v,0) + log(1+exp(-|v|)), hw exp/log
__device__ inline float softplus_f(float v) {
    return fmaxf(v, 0.f) + __logf(1.f + __expf(-fabsf(v)));
}

// ============ Kernel 0: convert x fp32 -> bf16 (whole tensor, one pass) ============
__global__ __launch_bounds__(256) void k_x2b(const float* __restrict__ x,
                                             short* __restrict__ xb, int n8) {
    int i = blockIdx.x * 256 + threadIdx.x;
    if (i >= n8) return;
    const float* src = x + (size_t)i * 8;
    float4 f0 = *(const float4*)src;
    float4 f1 = *(const float4*)(src + 4);
    short8 v; bf16 h;
    h = f2b(f0.x); v[0] = *(short*)&h;
    h = f2b(f0.y); v[1] = *(short*)&h;
    h = f2b(f0.z); v[2] = *(short*)&h;
    h = f2b(f0.w); v[3] = *(short*)&h;
    h = f2b(f1.x); v[4] = *(short*)&h;
    h = f2b(f1.y); v[5] = *(short*)&h;
    h = f2b(f1.z); v[6] = *(short*)&h;
    h = f2b(f1.w); v[7] = *(short*)&h;
    *(short8*)(xb + (size_t)i * 8) = v;
}

// ============ prep: motif-conv A-fragments (shift trick + align-shift 7) ============
__global__ __launch_bounds__(256) void k_prep_mot(const float* __restrict__ w_motif,
                                                  short* __restrict__ fragA) {
    int idx = blockIdx.x * 256 + threadIdx.x;
    if (idx >= 40 * 4 * 3 * 64 * 8) return;
    int i = idx & 7;
    int lane = (idx >> 3) & 63;
    int rest = idx >> 9;
    int qc = rest % 3; rest /= 3;
    int c = rest & 3; int o = rest >> 2;
    int dlt = lane & 15, kb = lane >> 4;
    int m = 32 * qc + 8 * kb + i;
    int k = m - 7 - dlt;
    float v = (k >= 0 && k < 51) ? w_motif[(o * 4 + c) * 51 + k] : 0.f;
    bf16 h = f2b(v);
    fragA[idx] = *(short*)&h;
}

// ============ Kernel 1: motif conv (4->40, K=51, pad25) + softplus via bf16 MFMA ============
#define MOT_BLKS 522
#define MOT_PAD  528
__global__ __launch_bounds__(256, 2) void k_motif_mfma(const short* __restrict__ xb,
        const short* __restrict__ fragA, const float* __restrict__ b_motif,
        bf16* __restrict__ y, int b0) {
    __shared__ __align__(16) short bwin[4][MOT_PAD * 8];   // 33,792 B
    const int tid = threadIdx.x;
    const int lane = tid & 63, wv = tid >> 6;
    const int wg = blockIdx.x, bl = blockIdx.y, og = blockIdx.z;
    const int bg = b0 + bl;
    const int L0 = wg * 4096;
    const int win0 = L0 - 32;
    const int ln15 = lane & 15, lkb = lane >> 4;

    short8 af[4][12];
    #pragma unroll
    for (int Mt = 0; Mt < 4; ++Mt)
        #pragma unroll
        for (int kq = 0; kq < 12; ++kq)
            af[Mt][kq] = *(const short8*)(fragA +
                (size_t)(((og * 4 + Mt) * 12 + kq) * 64 + lane) * 8);

    #pragma unroll 1
    for (int c = 0; c < 4; ++c) {
        const short* src = xb + ((size_t)bg * 4 + c) * LEN;
        for (int Lb = tid; Lb < MOT_BLKS; Lb += 256) {
            int gi = win0 + Lb * 8;
            short8 v;
            if (gi >= 0 && gi + 8 <= LEN) {
                v = *(const short8*)(src + gi);
            } else {
                #pragma unroll
                for (int j = 0; j < 8; ++j)
                    v[j] = (gi + j >= 0 && gi + j < LEN) ? src[gi + j] : (short)0;
            }
            int Pb = Lb ^ ((Lb >> 3) & 7);
            *(short8*)(&bwin[c][Pb * 8]) = v;
        }
    }
    __syncthreads();

    #pragma unroll 1
    for (int nt = 0; nt < 4; ++nt) {
        const int tt = wv * 4 + nt;
        f32x4 acc[4];
        #pragma unroll
        for (int Mt = 0; Mt < 4; ++Mt) acc[Mt] = (f32x4){0.f, 0.f, 0.f, 0.f};
        #pragma unroll
        for (int c = 0; c < 4; ++c) {
            #pragma unroll
            for (int qc = 0; qc < 3; ++qc) {
                int L = 32 * tt + 2 * ln15 + 4 * qc + lkb;
                int P = L ^ ((L >> 3) & 7);
                short8 bfr = *(const short8*)(&bwin[c][P * 8]);
                #pragma unroll
                for (int Mt = 0; Mt < 4; ++Mt)
                    acc[Mt] = __builtin_amdgcn_mfma_f32_16x16x32_bf16(
                        af[Mt][c * 3 + qc], bfr, acc[Mt], 0, 0, 0);
            }
        }
        #pragma unroll
        for (int Mt = 0; Mt < 4; ++Mt) {
            float bb = b_motif[og * 4 + Mt];
            int pos = L0 + tt * 256 + 16 * ln15 + 4 * lkb;
            ushort4 st; bf16 h;
            float v0 = softplus_f(acc[Mt][0] + bb);
            float v1 = softplus_f(acc[Mt][1] + bb);
            float v2 = softplus_f(acc[Mt][2] + bb);
            float v3 = softplus_f(acc[Mt][3] + bb);
            h = f2b(v0); st.x = *(unsigned short*)&h;
            h = f2b(v1); st.y = *(unsigned short*)&h;
            h = f2b(v2); st.z = *(unsigned short*)&h;
            h = f2b(v3); st.w = *(unsigned short*)&h;
            *(ushort4*)(&y[((size_t)bl * 40 + og * 4 + Mt) * LEN + pos]) = st;
        }
    }
}

// ============ Kernel 1b: reduce (40->4, 1x1) from y ============
__global__ __launch_bounds__(256) void k_reduce(const short* __restrict__ y,
        const float* __restrict__ w_reduce, const float* __restrict__ b_reduce,
        bf16* __restrict__ s1) {
    const int tid = threadIdx.x;
    const int bl = blockIdx.y;
    const int l8 = (blockIdx.x * 256 + tid) * 8;
    float s[4][8];
    #pragma unroll
    for (int c = 0; c < 4; ++c)
        #pragma unroll
        for (int e = 0; e < 8; ++e) s[c][e] = b_reduce[c];
    #pragma unroll 1
    for (int o = 0; o < 40; ++o) {
        short8 v = *(const short8*)(y + ((size_t)bl * 40 + o) * LEN + l8);
        float yv[8];
        #pragma unroll
        for (int e = 0; e < 8; ++e) yv[e] = us2f((unsigned short)v[e]);
        #pragma unroll
        for (int c = 0; c < 4; ++c) {
            float w = w_reduce[c * 40 + o];
            #pragma unroll
            for (int e = 0; e < 8; ++e) s[c][e] += w * yv[e];
        }
    }
    #pragma unroll
    for (int c = 0; c < 4; ++c) {
        short8 st; bf16 h;
        #pragma unroll
        for (int e = 0; e < 8; ++e) { h = f2b(s[c][e]); st[e] = *(short*)&h; }
        *(short8*)(&s1[((size_t)bl * 4 + c) * LEN + l8]) = st;
    }
}

// ============ prep: fft-conv A-fragments ============
__global__ __launch_bounds__(256) void k_prep_fft(const float* __restrict__ w_fft,
                                                  short* __restrict__ fragA) {
    int idx = blockIdx.x * 256 + threadIdx.x;
    if (idx >= 4 * 7 * 4 * 2 * 64 * 8) return;
    int i = idx & 7;
    int lane = (idx >> 3) & 63;
    int rest = idx >> 9;
    int ql = rest & 1; rest >>= 1;
    int Mt = rest & 3; rest >>= 2;
    int qb = rest % 7; int c = rest / 7;
    int dlt = lane & 15, kb = lane >> 4;
    int kkp = 32 * (qb * 2 + ql) + 8 * kb + i;
    int kk = kkp - dlt;
    float v = (kk >= 0 && kk < 401) ? w_fft[(Mt * 4 + c) * 401 + kk] : 0.f;
    bf16 h = f2b(v);
    fragA[idx] = *(short*)&h;
}

// ============ Kernel 2: fft conv (4->4, K=401, pad 200) via bf16 MFMA ============
#define FFT_BLKS 568
__global__ __launch_bounds__(256) void k_fft(const short* __restrict__ s1,
        const short* __restrict__ fragA, const float* __restrict__ b_fft,
        bf16* __restrict__ s2) {
    __shared__ __align__(16) short bwin[4][FFT_BLKS * 8];   // 36,352 B
    const int tid = threadIdx.x;
    const int lane = tid & 63, wv = tid >> 6;
    const int wg = blockIdx.x, bl = blockIdx.y;
    const int P0 = wg * 4096;
    const int win0 = P0 - 200;
    const int ln15 = lane & 15, lkb = lane >> 4;

    f32x4 acc[4][4];
    #pragma unroll
    for (int Mt = 0; Mt < 4; ++Mt)
        #pragma unroll
        for (int nt = 0; nt < 4; ++nt)
            acc[Mt][nt] = (f32x4){0.f, 0.f, 0.f, 0.f};

    #pragma unroll 1
    for (int cl = 0; cl < 4; ++cl) {
        const short* src = s1 + ((size_t)bl * 4 + cl) * LEN;
        for (int Lb = tid; Lb < FFT_BLKS; Lb += 256) {
            int gi = win0 + Lb * 8;
            short8 v;
            if (gi >= 0 && gi + 8 <= LEN) {
                v = *(const short8*)(src + gi);
            } else {
                #pragma unroll
                for (int j = 0; j < 8; ++j)
                    v[j] = (gi + j >= 0 && gi + j < LEN) ? src[gi + j] : (short)0;
            }
            int Pb = Lb ^ ((Lb >> 3) & 7);
            *(short8*)(&bwin[cl][Pb * 8]) = v;
        }
    }
    __syncthreads();

    #pragma unroll 1
    for (int cl = 0; cl < 4; ++cl) {
        #pragma unroll 1
        for (int qb = 0; qb < 7; ++qb) {
            short8 af[4][2];
            #pragma unroll
            for (int Mt = 0; Mt < 4; ++Mt)
                #pragma unroll
                for (int ql = 0; ql < 2; ++ql)
                    af[Mt][ql] = *(const short8*)(fragA +
                        (size_t)((((cl * 7 + qb) * 4 + Mt) * 2 + ql) * 64 + lane) * 8);
            #pragma unroll
            for (int nt = 0; nt < 4; ++nt) {
                const int tt = wv * 4 + nt;
                #pragma unroll
                for (int ql = 0; ql < 2; ++ql) {
                    int qc = qb * 2 + ql;
                    int L = 2 * ln15 + lkb + 4 * qc + 32 * tt;
                    int P = L ^ ((L >> 3) & 7);
                    short8 bfr = *(const short8*)(&bwin[cl][P * 8]);
                    #pragma unroll
                    for (int Mt = 0; Mt < 4; ++Mt)
                        acc[Mt][nt] = __builtin_amdgcn_mfma_f32_16x16x32_bf16(
                            af[Mt][ql], bfr, acc[Mt][nt], 0, 0, 0);
                }
            }
        }
    }

    #pragma unroll
    for (int Mt = 0; Mt < 4; ++Mt) {
        float bb = b_fft[Mt];
        #pragma unroll
        for (int nt = 0; nt < 4; ++nt) {
            int tt = wv * 4 + nt;
            int pos = P0 + tt * 256 + 16 * ln15 + 4 * lkb;
            ushort4 st; bf16 h;
            h = f2b(acc[Mt][nt][0] + bb); st.x = *(unsigned short*)&h;
            h = f2b(acc[Mt][nt][1] + bb); st.y = *(unsigned short*)&h;
            h = f2b(acc[Mt][nt][2] + bb); st.z = *(unsigned short*)&h;
            h = f2b(acc[Mt][nt][3] + bb); st.w = *(unsigned short*)&h;
            *(ushort4*)(&s2[((size_t)bl * 4 + Mt) * LEN + pos]) = st;
        }
    }
}

// ============ prep: effect-conv A-fragments ============
__global__ __launch_bounds__(256) void k_prep(const float* __restrict__ w_eff,
                                              short* __restrict__ fragA) {
    int idx = blockIdx.x * 256 + threadIdx.x;
    if (idx >= 40 * 4 * 2 * 5 * 64 * 8) return;
    int i = idx & 7;
    int lane = (idx >> 3) & 63;
    int rest = idx >> 9;
    int ql = rest % 5; rest /= 5;
    int Mt = rest & 1; rest >>= 1;
    int qb = rest & 3; int c = rest >> 2;
    int q = qb * 5 + ql;
    int dlt = lane & 15, kb = lane >> 4;
    int kp = 32 * q + 8 * kb + i;
    int kk = kp - dlt;
    float v = (kk >= 0 && kk < 601) ? w_eff[(Mt * 40 + c) * 601 + kk] : 0.f;
    bf16 h = __float2bfloat16(v);
    fragA[idx] = *(short*)&h;
}

// ============ Kernel 4: effect conv (40->2, K=601) + FUSED gate + sigmoid ============
// Tile 2048/WG. Wave-split K (wave owns channel wv of each chunk). v3: double-buffered
// bwin, ONE barrier per chunk — iteration cc gate-writes buf[(cc+1)&1] while computing
// chunk cc from buf[cc&1]; A-frag loads software-pipelined across unrolled qb loop.
#define EFF_NBLK 336
#define EFF_ITEMS (4 * EFF_NBLK)   // 1344
#define EFF_SH (EFF_NBLK * 8)      // shorts per channel window
__device__ __forceinline__ void eff_prefetch(const short* __restrict__ mact,
        size_t chanBase, int cc, int tid, int win0, short8 (&yreg)[6]) {
    #pragma unroll
    for (int it = 0; it < 6; ++it) {
        int idx = tid + it * 256;
        short8 v = {0, 0, 0, 0, 0, 0, 0, 0};
        if (idx < EFF_ITEMS) {
            int ch = idx / EFF_NBLK;
            int Lb = idx - ch * EFF_NBLK;
            int gi = win0 + Lb * 8;
            const short* src = mact + (chanBase + cc * 4 + ch) * (size_t)LEN;
            if (gi + 8 <= LEN) {
                v = *(const short8*)(src + gi);
            } else {
                #pragma unroll
                for (int j = 0; j < 8; ++j)
                    v[j] = (gi + j < LEN) ? src[gi + j] : (short)0;
            }
        }
        yreg[it] = v;
    }
}

__global__ __launch_bounds__(256, 2) void k_effect(const short* __restrict__ mact,
        const short* __restrict__ s2,
        const short* __restrict__ fragA,
        const float* __restrict__ w_expand, const float* __restrict__ b_expand,
        const float* __restrict__ b_eff,
        float* __restrict__ out, int b0) {
    // layout: bwin2[2][4][EFF_SH] | s2win[4][EFF_SH] | wexp | bexp  (65,312 B)
    __shared__ __align__(16) char smem[2 * 4 * EFF_SH * 2 + 4 * EFF_SH * 2 + 160 * 4 + 40 * 4];
    typedef short chanwin[EFF_SH];
    chanwin* bwin2[2];
    bwin2[0] = (chanwin*)smem;
    bwin2[1] = (chanwin*)(smem + 4 * EFF_SH * 2);
    chanwin* s2win = (chanwin*)(smem + 2 * 4 * EFF_SH * 2);
    float* wexp = (float*)(smem + 3 * 4 * EFF_SH * 2);
    float* bexp = wexp + 160;
    float* red  = (float*)smem;   // reduction scratch, reuses bwin2 after loop

    const int tid = threadIdx.x;
    const int lane = tid & 63, wv = tid >> 6;
    const int wgl = blockIdx.x, bl = blockIdx.y, bg = b0 + bl;
    const int L0 = wgl * 2048;
    const int win0 = L0 + 200;
    const int ln15 = lane & 15, lkb = lane >> 4;
    const size_t chanBase = (size_t)bl * 40;

    // stage expand weights + s2 window ONCE
    if (tid < 160) wexp[tid] = w_expand[tid];
    if (tid < 40) bexp[tid] = b_expand[tid];
    #pragma unroll 1
    for (int c = 0; c < 4; ++c) {
        const short* sp = s2 + ((size_t)bl * 4 + c) * LEN;
        for (int Lb = tid; Lb < EFF_NBLK; Lb += 256) {
            int gi = win0 + Lb * 8;
            short8 v = {0, 0, 0, 0, 0, 0, 0, 0};
            if (gi + 8 <= LEN) {
                v = *(const short8*)(sp + gi);
            } else {
                #pragma unroll
                for (int j = 0; j < 8; ++j)
                    v[j] = (gi + j < LEN) ? sp[gi + j] : (short)0;
            }
            *(short8*)(&s2win[c][Lb * 8]) = v;
        }
    }

    f32x4 acc[2][8];
    #pragma unroll
    for (int Mt = 0; Mt < 2; ++Mt)
        #pragma unroll
        for (int tt = 0; tt < 8; ++tt)
            acc[Mt][tt] = (f32x4){0.f, 0.f, 0.f, 0.f};

    short8 yreg[6];
    eff_prefetch(mact, chanBase, 0, tid, win0, yreg);
    __syncthreads();   // s2win + wexp ready

    // gate+write helper expanded inline via macro-ish lambda
    auto gate_write = [&](chanwin* dst, int cc) {
        #pragma unroll
        for (int it = 0; it < 6; ++it) {
            int idx = tid + it * 256;
            if (idx < EFF_ITEMS) {
                int ch = idx / EFF_NBLK;
                int Lb = idx - ch * EFF_NBLK;
                int o = cc * 4 + ch;
                float w0 = wexp[o * 4 + 0], w1 = wexp[o * 4 + 1];
                float w2 = wexp[o * 4 + 2], w3 = wexp[o * 4 + 3];
                float be = bexp[o];
                float s2v[4][8];
                #pragma unroll
                for (int c = 0; c < 4; ++c) {
                    short8 sv = *(const short8*)(&s2win[c][Lb * 8]);
                    #pragma unroll
                    for (int j = 0; j < 8; ++j) s2v[c][j] = us2f((unsigned short)sv[j]);
                }
                short8 w;
                #pragma unroll
                for (int j = 0; j < 8; ++j) {
                    float sg = be + w0 * s2v[0][j] + w1 * s2v[1][j]
                                  + w2 * s2v[2][j] + w3 * s2v[3][j];
                    float g = __builtin_amdgcn_rcpf(1.f + __expf(-sg));
                    float yv = us2f((unsigned short)yreg[it][j]) * g;
                    bf16 h = f2b(yv);
                    w[j] = *(short*)&h;
                }
                int P = Lb ^ ((Lb >> 3) & 7);
                *(short8*)(&dst[ch][P * 8]) = w;
            }
        }
    };

    // prologue: write chunk 0 into buf0; prefetch y for chunk 1
    gate_write(bwin2[0], 0);
    eff_prefetch(mact, chanBase, 1, tid, win0, yreg);
    __syncthreads();   // buf0 ready

    #pragma unroll 1
    for (int cc = 0; cc < 10; ++cc) {
        // overlapped: write chunk cc+1 into other buffer, prefetch y for cc+2
        if (cc < 9) {
            gate_write(bwin2[(cc + 1) & 1], cc + 1);
            if (cc < 8) eff_prefetch(mact, chanBase, cc + 2, tid, win0, yreg);
        }
        // compute chunk cc from buf[cc&1], wave's channel only (cl = wv)
        const chanwin* buf = bwin2[cc & 1];
        const int cg = cc * 4 + wv;
        short8 afc[2][5], afn[2][5];
        #pragma unroll
        for (int Mt = 0; Mt < 2; ++Mt)
            #pragma unroll
            for (int ql = 0; ql < 5; ++ql)
                afc[Mt][ql] = *(const short8*)(fragA +
                    (size_t)(((((cg * 4 + 0) * 2 + Mt) * 5 + ql) * 64 + lane) * 8));
        #pragma unroll
        for (int qb = 0; qb < 4; ++qb) {
            if (qb < 3) {
                #pragma unroll
                for (int Mt = 0; Mt < 2; ++Mt)
                    #pragma unroll
                    for (int ql = 0; ql < 5; ++ql)
                        afn[Mt][ql] = *(const short8*)(fragA +
                            (size_t)(((((cg * 4 + qb + 1) * 2 + Mt) * 5 + ql) * 64 + lane) * 8));
            }
            #pragma unroll
            for (int tt = 0; tt < 8; ++tt) {
                #pragma unroll
                for (int ql = 0; ql < 5; ++ql) {
                    int q = qb * 5 + ql;
                    int L = 32 * tt + 2 * ln15 + 4 * q + lkb;
                    int P = L ^ ((L >> 3) & 7);
                    short8 bfr = *(const short8*)(&buf[wv][P * 8]);
                    acc[0][tt] = __builtin_amdgcn_mfma_f32_16x16x32_bf16(
                        afc[0][ql], bfr, acc[0][tt], 0, 0, 0);
                    acc[1][tt] = __builtin_amdgcn_mfma_f32_16x16x32_bf16(
                        afc[1][ql], bfr, acc[1][tt], 0, 0, 0);
                }
            }
            if (qb < 3) {
                #pragma unroll
                for (int Mt = 0; Mt < 2; ++Mt)
                    #pragma unroll
                    for (int ql = 0; ql < 5; ++ql)
                        afc[Mt][ql] = afn[Mt][ql];
            }
        }
        __syncthreads();   // buf[(cc+1)&1] ready; compute(cc) done
    }

    // ---- cross-wave reduction (bwin2/s2win dead) ----
    if (wv == 1 || wv == 3) {
        float* p = red + (wv >> 1) * 4096;
        #pragma unroll
        for (int Mt = 0; Mt < 2; ++Mt)
            #pragma unroll
            for (int tt = 0; tt < 8; ++tt)
                *(f32x4*)(p + (Mt * 8 + tt) * 256 + lane * 4) = acc[Mt][tt];
    }
    __syncthreads();
    if (wv == 0 || wv == 2) {
        float* p = red + (wv >> 1) * 4096;
        #pragma unroll
        for (int Mt = 0; Mt < 2; ++Mt)
            #pragma unroll
            for (int tt = 0; tt < 8; ++tt)
                acc[Mt][tt] += *(const f32x4*)(p + (Mt * 8 + tt) * 256 + lane * 4);
    }
    __syncthreads();
    if (wv == 2) {
        #pragma unroll
        for (int Mt = 0; Mt < 2; ++Mt)
            #pragma unroll
            for (int tt = 0; tt < 8; ++tt)
                *(f32x4*)(red + (Mt * 8 + tt) * 256 + lane * 4) = acc[Mt][tt];
    }
    __syncthreads();
    if (wv == 0) {
        const float be0 = b_eff[0], be1 = b_eff[1];
        #pragma unroll
        for (int Mt = 0; Mt < 2; ++Mt) {
            float bb = Mt ? be1 : be0;
            #pragma unroll
            for (int tt = 0; tt < 8; ++tt) {
                f32x4 a = acc[Mt][tt];
                a += *(const f32x4*)(red + (Mt * 8 + tt) * 256 + lane * 4);
                int pos = L0 + tt * 256 + 16 * ln15 + 4 * lkb;
                if (pos < LOUT) {
                    float4 st;
                    st.x = __builtin_amdgcn_rcpf(1.f + __expf(-(a[0] + bb)));
                    st.y = __builtin_amdgcn_rcpf(1.f + __expf(-(a[1] + bb)));
                    st.z = __builtin_amdgcn_rcpf(1.f + __expf(-(a[2] + bb)));
                    st.w = __builtin_amdgcn_rcpf(1.f + __expf(-(a[3] + bb)));
                    *(float4*)(&out[((size_t)bg * 2 + Mt) * LOUT + pos]) = st;
                }
            }
        }
    }
}

extern "C" void kernel_launch(void* const* d_in, const int* in_sizes, int n_in,
                              void* d_out, int out_size, void* d_ws, size_t ws_size,
                              hipStream_t stream) {
    const float* x        = (const float*)d_in[0];
    const float* w_motif  = (const float*)d_in[1];
    const float* b_motif  = (const float*)d_in[2];
    const float* w_reduce = (const float*)d_in[3];
    const float* b_reduce = (const float*)d_in[4];
    const float* w_fft    = (const float*)d_in[5];
    const float* b_fft    = (const float*)d_in[6];
    const float* w_expand = (const float*)d_in[7];
    const float* b_expand = (const float*)d_in[8];
    const float* w_eff    = (const float*)d_in[9];
    const float* b_eff    = (const float*)d_in[10];
    float* out = (float*)d_out;

    const size_t FRAGA_EFF = (size_t)40 * 4 * 2 * 5 * 64 * 8 * 2;  // 1,638,400
    const size_t FRAGA_FFT = (size_t)4 * 7 * 4 * 2 * 64 * 8 * 2;   //   229,376
    const size_t FRAGA_MOT = (size_t)40 * 4 * 3 * 64 * 8 * 2;      //   491,520
    const size_t XB_B      = (size_t)32 * 4 * LEN * 2;             // 16,777,216
    const size_t HEAD = FRAGA_EFF + FRAGA_FFT + FRAGA_MOT + XB_B;

    short* fragA_eff = (short*)d_ws;
    short* fragA_fft = (short*)((char*)d_ws + FRAGA_EFF);
    short* fragA_mot = (short*)((char*)d_ws + FRAGA_EFF + FRAGA_FFT);
    short* xb        = (short*)((char*)d_ws + FRAGA_EFF + FRAGA_FFT + FRAGA_MOT);
    char*  rest      = (char*)d_ws + HEAD;

    const size_t PB_Y = (size_t)40 * LEN * 2;   // y bf16
    const size_t PB_S = (size_t)4 * LEN * 2;    // s1/s2 bf16
    const size_t PERB = PB_Y + 2 * PB_S;
    size_t avail = (ws_size > HEAD) ? (ws_size - HEAD) : 0;
    int nb = (int)(avail / PERB);
    if (nb > 32) nb = 32;
    if (nb < 1) nb = 1;

    bf16* y  = (bf16*)rest;
    bf16* s1 = (bf16*)(rest + PB_Y * (size_t)nb);
    bf16* s2 = (bf16*)(rest + (PB_Y + PB_S) * (size_t)nb);

    hipLaunchKernelGGL(k_prep,     dim3(3200), dim3(256), 0, stream, w_eff, fragA_eff);
    hipLaunchKernelGGL(k_prep_fft, dim3(448),  dim3(256), 0, stream, w_fft, fragA_fft);
    hipLaunchKernelGGL(k_prep_mot, dim3(960),  dim3(256), 0, stream, w_motif, fragA_mot);
    hipLaunchKernelGGL(k_x2b,      dim3(4096), dim3(256), 0, stream, x, xb,
                       (int)(32 * 4 * LEN / 8));

    for (int b0 = 0; b0 < 32; b0 += nb) {
        int nbb = (32 - b0 < nb) ? (32 - b0) : nb;
        hipLaunchKernelGGL(k_motif_mfma, dim3(16, nbb, 10), dim3(256), 0, stream,
                           xb, fragA_mot, b_motif, y, b0);
        hipLaunchKernelGGL(k_reduce, dim3(32, nbb), dim3(256), 0, stream,
                           (const short*)y, w_reduce, b_reduce, s1);
        hipLaunchKernelGGL(k_fft, dim3(16, nbb), dim3(256), 0, stream,
                           (const short*)s1, fragA_fft, b_fft, s2);
        hipLaunchKernelGGL(k_effect, dim3(32, nbb), dim3(256), 0, stream,
                           (const short*)y, (const short*)s2, fragA_eff,
                           w_expand, b_expand, b_eff, out, b0);
    }
}

// Round 11
// 453.525 us; speedup vs baseline: 5.0070x; 5.0070x over previous
//
#include <hip/hip_runtime.h>
#include <hip/hip_bf16.h>
#include <math.h>

#define LEN 65536
#define LOUT 64536
typedef __hip_bfloat16 bf16;
typedef __attribute__((ext_vector_type(8))) short short8;
typedef __attribute__((ext_vector_type(4))) float f32x4;

__device__ inline float b2f(bf16 h) { return __bfloat162float(h); }
__device__ inline bf16 f2b(float f) { return __float2bfloat16(f); }
__device__ inline float us2f(unsigned short u) { bf16 h = *(bf16*)&u; return __bfloat162float(h); }
// cheap softplus: max(v,0) + log(1+exp(-|v|)), hw exp/log
__device__ inline float softplus_f(float v) {
    return fmaxf(v, 0.f) + __logf(1.f + __expf(-fabsf(v)));
}

// ============ Kernel 0: convert x fp32 -> bf16 (whole tensor, one pass) ============
__global__ __launch_bounds__(256) void k_x2b(const float* __restrict__ x,
                                             short* __restrict__ xb, int n8) {
    int i = blockIdx.x * 256 + threadIdx.x;
    if (i >= n8) return;
    const float* src = x + (size_t)i * 8;
    float4 f0 = *(const float4*)src;
    float4 f1 = *(const float4*)(src + 4);
    short8 v; bf16 h;
    h = f2b(f0.x); v[0] = *(short*)&h;
    h = f2b(f0.y); v[1] = *(short*)&h;
    h = f2b(f0.z); v[2] = *(short*)&h;
    h = f2b(f0.w); v[3] = *(short*)&h;
    h = f2b(f1.x); v[4] = *(short*)&h;
    h = f2b(f1.y); v[5] = *(short*)&h;
    h = f2b(f1.z); v[6] = *(short*)&h;
    h = f2b(f1.w); v[7] = *(short*)&h;
    *(short8*)(xb + (size_t)i * 8) = v;
}

// ============ prep: motif-conv A-fragments (shift trick + align-shift 7) ============
__global__ __launch_bounds__(256) void k_prep_mot(const float* __restrict__ w_motif,
                                                  short* __restrict__ fragA) {
    int idx = blockIdx.x * 256 + threadIdx.x;
    if (idx >= 40 * 4 * 3 * 64 * 8) return;
    int i = idx & 7;
    int lane = (idx >> 3) & 63;
    int rest = idx >> 9;
    int qc = rest % 3; rest /= 3;
    int c = rest & 3; int o = rest >> 2;
    int dlt = lane & 15, kb = lane >> 4;
    int m = 32 * qc + 8 * kb + i;
    int k = m - 7 - dlt;
    float v = (k >= 0 && k < 51) ? w_motif[(o * 4 + c) * 51 + k] : 0.f;
    bf16 h = f2b(v);
    fragA[idx] = *(short*)&h;
}

// ============ Kernel 1: motif conv (4->40, K=51, pad25) + softplus via bf16 MFMA ============
#define MOT_BLKS 522
#define MOT_PAD  528
__global__ __launch_bounds__(256, 2) void k_motif_mfma(const short* __restrict__ xb,
        const short* __restrict__ fragA, const float* __restrict__ b_motif,
        bf16* __restrict__ y, int b0) {
    __shared__ __align__(16) short bwin[4][MOT_PAD * 8];   // 33,792 B
    const int tid = threadIdx.x;
    const int lane = tid & 63, wv = tid >> 6;
    const int wg = blockIdx.x, bl = blockIdx.y, og = blockIdx.z;
    const int bg = b0 + bl;
    const int L0 = wg * 4096;
    const int win0 = L0 - 32;
    const int ln15 = lane & 15, lkb = lane >> 4;

    short8 af[4][12];
    #pragma unroll
    for (int Mt = 0; Mt < 4; ++Mt)
        #pragma unroll
        for (int kq = 0; kq < 12; ++kq)
            af[Mt][kq] = *(const short8*)(fragA +
                (size_t)(((og * 4 + Mt) * 12 + kq) * 64 + lane) * 8);

    #pragma unroll 1
    for (int c = 0; c < 4; ++c) {
        const short* src = xb + ((size_t)bg * 4 + c) * LEN;
        for (int Lb = tid; Lb < MOT_BLKS; Lb += 256) {
            int gi = win0 + Lb * 8;
            short8 v;
            if (gi >= 0 && gi + 8 <= LEN) {
                v = *(const short8*)(src + gi);
            } else {
                #pragma unroll
                for (int j = 0; j < 8; ++j)
                    v[j] = (gi + j >= 0 && gi + j < LEN) ? src[gi + j] : (short)0;
            }
            int Pb = Lb ^ ((Lb >> 3) & 7);
            *(short8*)(&bwin[c][Pb * 8]) = v;
        }
    }
    __syncthreads();

    #pragma unroll 1
    for (int nt = 0; nt < 4; ++nt) {
        const int tt = wv * 4 + nt;
        f32x4 acc[4];
        #pragma unroll
        for (int Mt = 0; Mt < 4; ++Mt) acc[Mt] = (f32x4){0.f, 0.f, 0.f, 0.f};
        #pragma unroll
        for (int c = 0; c < 4; ++c) {
            #pragma unroll
            for (int qc = 0; qc < 3; ++qc) {
                int L = 32 * tt + 2 * ln15 + 4 * qc + lkb;
                int P = L ^ ((L >> 3) & 7);
                short8 bfr = *(const short8*)(&bwin[c][P * 8]);
                #pragma unroll
                for (int Mt = 0; Mt < 4; ++Mt)
                    acc[Mt] = __builtin_amdgcn_mfma_f32_16x16x32_bf16(
                        af[Mt][c * 3 + qc], bfr, acc[Mt], 0, 0, 0);
            }
        }
        #pragma unroll
        for (int Mt = 0; Mt < 4; ++Mt) {
            float bb = b_motif[og * 4 + Mt];
            int pos = L0 + tt * 256 + 16 * ln15 + 4 * lkb;
            ushort4 st; bf16 h;
            float v0 = softplus_f(acc[Mt][0] + bb);
            float v1 = softplus_f(acc[Mt][1] + bb);
            float v2 = softplus_f(acc[Mt][2] + bb);
            float v3 = softplus_f(acc[Mt][3] + bb);
            h = f2b(v0); st.x = *(unsigned short*)&h;
            h = f2b(v1); st.y = *(unsigned short*)&h;
            h = f2b(v2); st.z = *(unsigned short*)&h;
            h = f2b(v3); st.w = *(unsigned short*)&h;
            *(ushort4*)(&y[((size_t)bl * 40 + og * 4 + Mt) * LEN + pos]) = st;
        }
    }
}

// ============ Kernel 1b: reduce (40->4, 1x1) from y ============
__global__ __launch_bounds__(256) void k_reduce(const short* __restrict__ y,
        const float* __restrict__ w_reduce, const float* __restrict__ b_reduce,
        bf16* __restrict__ s1) {
    const int tid = threadIdx.x;
    const int bl = blockIdx.y;
    const int l8 = (blockIdx.x * 256 + tid) * 8;
    float s[4][8];
    #pragma unroll
    for (int c = 0; c < 4; ++c)
        #pragma unroll
        for (int e = 0; e < 8; ++e) s[c][e] = b_reduce[c];
    #pragma unroll 1
    for (int o = 0; o < 40; ++o) {
        short8 v = *(const short8*)(y + ((size_t)bl * 40 + o) * LEN + l8);
        float yv[8];
        #pragma unroll
        for (int e = 0; e < 8; ++e) yv[e] = us2f((unsigned short)v[e]);
        #pragma unroll
        for (int c = 0; c < 4; ++c) {
            float w = w_reduce[c * 40 + o];
            #pragma unroll
            for (int e = 0; e < 8; ++e) s[c][e] += w * yv[e];
        }
    }
    #pragma unroll
    for (int c = 0; c < 4; ++c) {
        short8 st; bf16 h;
        #pragma unroll
        for (int e = 0; e < 8; ++e) { h = f2b(s[c][e]); st[e] = *(short*)&h; }
        *(short8*)(&s1[((size_t)bl * 4 + c) * LEN + l8]) = st;
    }
}

// ============ prep: fft-conv A-fragments ============
__global__ __launch_bounds__(256) void k_prep_fft(const float* __restrict__ w_fft,
                                                  short* __restrict__ fragA) {
    int idx = blockIdx.x * 256 + threadIdx.x;
    if (idx >= 4 * 7 * 4 * 2 * 64 * 8) return;
    int i = idx & 7;
    int lane = (idx >> 3) & 63;
    int rest = idx >> 9;
    int ql = rest & 1; rest >>= 1;
    int Mt = rest & 3; rest >>= 2;
    int qb = rest % 7; int c = rest / 7;
    int dlt = lane & 15, kb = lane >> 4;
    int kkp = 32 * (qb * 2 + ql) + 8 * kb + i;
    int kk = kkp - dlt;
    float v = (kk >= 0 && kk < 401) ? w_fft[(Mt * 4 + c) * 401 + kk] : 0.f;
    bf16 h = f2b(v);
    fragA[idx] = *(short*)&h;
}

// ============ Kernel 2: fft conv (4->4, K=401, pad 200) via bf16 MFMA ============
#define FFT_BLKS 568
__global__ __launch_bounds__(256) void k_fft(const short* __restrict__ s1,
        const short* __restrict__ fragA, const float* __restrict__ b_fft,
        bf16* __restrict__ s2) {
    __shared__ __align__(16) short bwin[4][FFT_BLKS * 8];   // 36,352 B
    const int tid = threadIdx.x;
    const int lane = tid & 63, wv = tid >> 6;
    const int wg = blockIdx.x, bl = blockIdx.y;
    const int P0 = wg * 4096;
    const int win0 = P0 - 200;
    const int ln15 = lane & 15, lkb = lane >> 4;

    f32x4 acc[4][4];
    #pragma unroll
    for (int Mt = 0; Mt < 4; ++Mt)
        #pragma unroll
        for (int nt = 0; nt < 4; ++nt)
            acc[Mt][nt] = (f32x4){0.f, 0.f, 0.f, 0.f};

    #pragma unroll 1
    for (int cl = 0; cl < 4; ++cl) {
        const short* src = s1 + ((size_t)bl * 4 + cl) * LEN;
        for (int Lb = tid; Lb < FFT_BLKS; Lb += 256) {
            int gi = win0 + Lb * 8;
            short8 v;
            if (gi >= 0 && gi + 8 <= LEN) {
                v = *(const short8*)(src + gi);
            } else {
                #pragma unroll
                for (int j = 0; j < 8; ++j)
                    v[j] = (gi + j >= 0 && gi + j < LEN) ? src[gi + j] : (short)0;
            }
            int Pb = Lb ^ ((Lb >> 3) & 7);
            *(short8*)(&bwin[cl][Pb * 8]) = v;
        }
    }
    __syncthreads();

    #pragma unroll 1
    for (int cl = 0; cl < 4; ++cl) {
        #pragma unroll 1
        for (int qb = 0; qb < 7; ++qb) {
            short8 af[4][2];
            #pragma unroll
            for (int Mt = 0; Mt < 4; ++Mt)
                #pragma unroll
                for (int ql = 0; ql < 2; ++ql)
                    af[Mt][ql] = *(const short8*)(fragA +
                        (size_t)((((cl * 7 + qb) * 4 + Mt) * 2 + ql) * 64 + lane) * 8);
            #pragma unroll
            for (int nt = 0; nt < 4; ++nt) {
                const int tt = wv * 4 + nt;
                #pragma unroll
                for (int ql = 0; ql < 2; ++ql) {
                    int qc = qb * 2 + ql;
                    int L = 2 * ln15 + lkb + 4 * qc + 32 * tt;
                    int P = L ^ ((L >> 3) & 7);
                    short8 bfr = *(const short8*)(&bwin[cl][P * 8]);
                    #pragma unroll
                    for (int Mt = 0; Mt < 4; ++Mt)
                        acc[Mt][nt] = __builtin_amdgcn_mfma_f32_16x16x32_bf16(
                            af[Mt][ql], bfr, acc[Mt][nt], 0, 0, 0);
                }
            }
        }
    }

    #pragma unroll
    for (int Mt = 0; Mt < 4; ++Mt) {
        float bb = b_fft[Mt];
        #pragma unroll
        for (int nt = 0; nt < 4; ++nt) {
            int tt = wv * 4 + nt;
            int pos = P0 + tt * 256 + 16 * ln15 + 4 * lkb;
            ushort4 st; bf16 h;
            h = f2b(acc[Mt][nt][0] + bb); st.x = *(unsigned short*)&h;
            h = f2b(acc[Mt][nt][1] + bb); st.y = *(unsigned short*)&h;
            h = f2b(acc[Mt][nt][2] + bb); st.z = *(unsigned short*)&h;
            h = f2b(acc[Mt][nt][3] + bb); st.w = *(unsigned short*)&h;
            *(ushort4*)(&s2[((size_t)bl * 4 + Mt) * LEN + pos]) = st;
        }
    }
}

// ============ prep: effect-conv A-fragments ============
__global__ __launch_bounds__(256) void k_prep(const float* __restrict__ w_eff,
                                              short* __restrict__ fragA) {
    int idx = blockIdx.x * 256 + threadIdx.x;
    if (idx >= 40 * 4 * 2 * 5 * 64 * 8) return;
    int i = idx & 7;
    int lane = (idx >> 3) & 63;
    int rest = idx >> 9;
    int ql = rest % 5; rest /= 5;
    int Mt = rest & 1; rest >>= 1;
    int qb = rest & 3; int c = rest >> 2;
    int q = qb * 5 + ql;
    int dlt = lane & 15, kb = lane >> 4;
    int kp = 32 * q + 8 * kb + i;
    int kk = kp - dlt;
    float v = (kk >= 0 && kk < 601) ? w_eff[(Mt * 40 + c) * 601 + kk] : 0.f;
    bf16 h = __float2bfloat16(v);
    fragA[idx] = *(short*)&h;
}

// ============ Kernel 4: effect conv (40->2, K=601) + FUSED gate, partials ============
// v4 = round-9 proven body + CHANNEL SPLIT across blockIdx.z (2 halves x 20 ch = 5 chunks).
// Grid (32, nb, 2) = 2048 WGs -> 8/CU depth. Each half writes fp32 partial sums to ws;
// k_comb adds halves + bias + sigmoid. Wave-split K (wave owns channel wv of chunk).
#define EFF_NBLK 336
#define EFF_ITEMS (4 * EFF_NBLK)   // 1344
#define EFF_SH (EFF_NBLK * 8)      // shorts per channel window
__device__ __forceinline__ void eff_prefetch(const short* __restrict__ mact,
        size_t chanBase, int cc, int tid, int win0, short8 (&yreg)[6]) {
    #pragma unroll
    for (int it = 0; it < 6; ++it) {
        int idx = tid + it * 256;
        short8 v = {0, 0, 0, 0, 0, 0, 0, 0};
        if (idx < EFF_ITEMS) {
            int ch = idx / EFF_NBLK;
            int Lb = idx - ch * EFF_NBLK;
            int gi = win0 + Lb * 8;
            const short* src = mact + (chanBase + cc * 4 + ch) * (size_t)LEN;
            if (gi + 8 <= LEN) {
                v = *(const short8*)(src + gi);
            } else {
                #pragma unroll
                for (int j = 0; j < 8; ++j)
                    v[j] = (gi + j < LEN) ? src[gi + j] : (short)0;
            }
        }
        yreg[it] = v;
    }
}

__global__ __launch_bounds__(256, 3) void k_effect(const short* __restrict__ mact,
        const short* __restrict__ s2,
        const short* __restrict__ fragA,
        const float* __restrict__ w_expand, const float* __restrict__ b_expand,
        float* __restrict__ part) {
    // carved shared block: bwin | s2win | wexp | bexp ; reduction reuses bwin+s2win
    __shared__ __align__(16) char smem[2 * EFF_SH * 4 * 2 + 160 * 4 + 40 * 4];
    short (*bwin)[EFF_SH]  = (short(*)[EFF_SH])smem;
    short (*s2win)[EFF_SH] = (short(*)[EFF_SH])(smem + EFF_SH * 4 * 2);
    float* wexp = (float*)(smem + 2 * EFF_SH * 4 * 2);
    float* bexp = wexp + 160;
    float* red  = (float*)smem;   // 32 KB scratch, used after cc loop

    const int tid = threadIdx.x;
    const int lane = tid & 63, wv = tid >> 6;
    const int wgl = blockIdx.x, bl = blockIdx.y, half = blockIdx.z;
    const int coff = half * 20;          // channel offset of this half
    const int L0 = wgl * 2048;
    const int win0 = L0 + 200;
    const int ln15 = lane & 15, lkb = lane >> 4;
    const size_t chanBase = (size_t)bl * 40 + coff;

    // stage expand weights + s2 window ONCE (consumed after loop-top barrier)
    if (tid < 160) wexp[tid] = w_expand[tid];
    if (tid < 40) bexp[tid] = b_expand[tid];
    #pragma unroll 1
    for (int c = 0; c < 4; ++c) {
        const short* sp = s2 + ((size_t)bl * 4 + c) * LEN;
        for (int Lb = tid; Lb < EFF_NBLK; Lb += 256) {
            int gi = win0 + Lb * 8;
            short8 v = {0, 0, 0, 0, 0, 0, 0, 0};
            if (gi + 8 <= LEN) {
                v = *(const short8*)(sp + gi);
            } else {
                #pragma unroll
                for (int j = 0; j < 8; ++j)
                    v[j] = (gi + j < LEN) ? sp[gi + j] : (short)0;
            }
            *(short8*)(&s2win[c][Lb * 8]) = v;
        }
    }

    f32x4 acc[2][8];   // [Mt][tt] — this wave's partial (its channel slice)
    #pragma unroll
    for (int Mt = 0; Mt < 2; ++Mt)
        #pragma unroll
        for (int tt = 0; tt < 8; ++tt)
            acc[Mt][tt] = (f32x4){0.f, 0.f, 0.f, 0.f};

    short8 yreg[6];
    eff_prefetch(mact, chanBase, 0, tid, win0, yreg);

    #pragma unroll 1
    for (int cc = 0; cc < 5; ++cc) {
        __syncthreads();
        // ---- write phase: gate( y, s2win ) -> swizzled bwin (all waves, all ch) ----
        #pragma unroll
        for (int it = 0; it < 6; ++it) {
            int idx = tid + it * 256;
            if (idx < EFF_ITEMS) {
                int ch = idx / EFF_NBLK;
                int Lb = idx - ch * EFF_NBLK;
                int o = coff + cc * 4 + ch;
                float w0 = wexp[o * 4 + 0], w1 = wexp[o * 4 + 1];
                float w2 = wexp[o * 4 + 2], w3 = wexp[o * 4 + 3];
                float be = bexp[o];
                float s2v[4][8];
                #pragma unroll
                for (int c = 0; c < 4; ++c) {
                    short8 sv = *(const short8*)(&s2win[c][Lb * 8]);
                    #pragma unroll
                    for (int j = 0; j < 8; ++j) s2v[c][j] = us2f((unsigned short)sv[j]);
                }
                short8 w;
                #pragma unroll
                for (int j = 0; j < 8; ++j) {
                    float sg = be + w0 * s2v[0][j] + w1 * s2v[1][j]
                                  + w2 * s2v[2][j] + w3 * s2v[3][j];
                    float g = __builtin_amdgcn_rcpf(1.f + __expf(-sg));
                    float yv = us2f((unsigned short)yreg[it][j]) * g;
                    bf16 h = f2b(yv);
                    w[j] = *(short*)&h;
                }
                int P = Lb ^ ((Lb >> 3) & 7);
                *(short8*)(&bwin[ch][P * 8]) = w;
            }
        }
        __syncthreads();
        // ---- T14: issue next chunk's y loads (land during compute) ----
        if (cc < 4) eff_prefetch(mact, chanBase, cc + 1, tid, win0, yreg);
        // ---- compute phase: this wave's channel only (cl = wv) ----
        const int cg = coff + cc * 4 + wv;
        #pragma unroll 1
        for (int qb = 0; qb < 4; ++qb) {
            short8 af[2][5];
            #pragma unroll
            for (int Mt = 0; Mt < 2; ++Mt)
                #pragma unroll
                for (int ql = 0; ql < 5; ++ql)
                    af[Mt][ql] = *(const short8*)(fragA +
                        (size_t)(((((cg * 4 + qb) * 2 + Mt) * 5 + ql) * 64 + lane) * 8));
            #pragma unroll
            for (int tt = 0; tt < 8; ++tt) {
                #pragma unroll
                for (int ql = 0; ql < 5; ++ql) {
                    int q = qb * 5 + ql;
                    int L = 32 * tt + 2 * ln15 + 4 * q + lkb;
                    int P = L ^ ((L >> 3) & 7);
                    short8 bfr = *(const short8*)(&bwin[wv][P * 8]);
                    acc[0][tt] = __builtin_amdgcn_mfma_f32_16x16x32_bf16(
                        af[0][ql], bfr, acc[0][tt], 0, 0, 0);
                    acc[1][tt] = __builtin_amdgcn_mfma_f32_16x16x32_bf16(
                        af[1][ql], bfr, acc[1][tt], 0, 0, 0);
                }
            }
        }
    }

    // ---- cross-wave reduction: acc_total = sum over waves (bwin/s2win dead) ----
    __syncthreads();
    if (wv == 1 || wv == 3) {
        float* p = red + (wv >> 1) * 4096;
        #pragma unroll
        for (int Mt = 0; Mt < 2; ++Mt)
            #pragma unroll
            for (int tt = 0; tt < 8; ++tt)
                *(f32x4*)(p + (Mt * 8 + tt) * 256 + lane * 4) = acc[Mt][tt];
    }
    __syncthreads();
    if (wv == 0 || wv == 2) {
        float* p = red + (wv >> 1) * 4096;
        #pragma unroll
        for (int Mt = 0; Mt < 2; ++Mt)
            #pragma unroll
            for (int tt = 0; tt < 8; ++tt)
                acc[Mt][tt] += *(const f32x4*)(p + (Mt * 8 + tt) * 256 + lane * 4);
    }
    __syncthreads();
    if (wv == 2) {
        #pragma unroll
        for (int Mt = 0; Mt < 2; ++Mt)
            #pragma unroll
            for (int tt = 0; tt < 8; ++tt)
                *(f32x4*)(red + (Mt * 8 + tt) * 256 + lane * 4) = acc[Mt][tt];
    }
    __syncthreads();
    if (wv == 0) {
        // write fp32 partial (no bias/sigmoid) to part[bl][half][Mt][pos]
        #pragma unroll
        for (int Mt = 0; Mt < 2; ++Mt) {
            #pragma unroll
            for (int tt = 0; tt < 8; ++tt) {
                f32x4 a = acc[Mt][tt];
                a += *(const f32x4*)(red + (Mt * 8 + tt) * 256 + lane * 4);
                int pos = L0 + tt * 256 + 16 * ln15 + 4 * lkb;
                float4 st; st.x = a[0]; st.y = a[1]; st.z = a[2]; st.w = a[3];
                *(float4*)(&part[(((size_t)bl * 2 + half) * 2 + Mt) * LEN + pos]) = st;
            }
        }
    }
}

// ============ Kernel 5: combine partials + bias + sigmoid -> out ============
__global__ __launch_bounds__(256) void k_comb(const float* __restrict__ part,
        const float* __restrict__ b_eff, float* __restrict__ out, int b0) {
    const int tid = threadIdx.x;
    const int bl = blockIdx.y, bg = b0 + bl;
    int l4 = (blockIdx.x * 256 + tid) * 4;
    if (l4 >= LOUT) return;
    #pragma unroll
    for (int Mt = 0; Mt < 2; ++Mt) {
        float bb = b_eff[Mt];
        float4 p0 = *(const float4*)(&part[(((size_t)bl * 2 + 0) * 2 + Mt) * LEN + l4]);
        float4 p1 = *(const float4*)(&part[(((size_t)bl * 2 + 1) * 2 + Mt) * LEN + l4]);
        float4 st;
        st.x = __builtin_amdgcn_rcpf(1.f + __expf(-(p0.x + p1.x + bb)));
        st.y = __builtin_amdgcn_rcpf(1.f + __expf(-(p0.y + p1.y + bb)));
        st.z = __builtin_amdgcn_rcpf(1.f + __expf(-(p0.z + p1.z + bb)));
        st.w = __builtin_amdgcn_rcpf(1.f + __expf(-(p0.w + p1.w + bb)));
        *(float4*)(&out[((size_t)bg * 2 + Mt) * LOUT + l4]) = st;
    }
}

extern "C" void kernel_launch(void* const* d_in, const int* in_sizes, int n_in,
                              void* d_out, int out_size, void* d_ws, size_t ws_size,
                              hipStream_t stream) {
    const float* x        = (const float*)d_in[0];
    const float* w_motif  = (const float*)d_in[1];
    const float* b_motif  = (const float*)d_in[2];
    const float* w_reduce = (const float*)d_in[3];
    const float* b_reduce = (const float*)d_in[4];
    const float* w_fft    = (const float*)d_in[5];
    const float* b_fft    = (const float*)d_in[6];
    const float* w_expand = (const float*)d_in[7];
    const float* b_expand = (const float*)d_in[8];
    const float* w_eff    = (const float*)d_in[9];
    const float* b_eff    = (const float*)d_in[10];
    float* out = (float*)d_out;

    const size_t FRAGA_EFF = (size_t)40 * 4 * 2 * 5 * 64 * 8 * 2;  // 1,638,400
    const size_t FRAGA_FFT = (size_t)4 * 7 * 4 * 2 * 64 * 8 * 2;   //   229,376
    const size_t FRAGA_MOT = (size_t)40 * 4 * 3 * 64 * 8 * 2;      //   491,520
    const size_t XB_B      = (size_t)32 * 4 * LEN * 2;             // 16,777,216
    const size_t HEAD = FRAGA_EFF + FRAGA_FFT + FRAGA_MOT + XB_B;

    short* fragA_eff = (short*)d_ws;
    short* fragA_fft = (short*)((char*)d_ws + FRAGA_EFF);
    short* fragA_mot = (short*)((char*)d_ws + FRAGA_EFF + FRAGA_FFT);
    short* xb        = (short*)((char*)d_ws + FRAGA_EFF + FRAGA_FFT + FRAGA_MOT);
    char*  rest      = (char*)d_ws + HEAD;

    const size_t PB_Y = (size_t)40 * LEN * 2;   // y bf16:            5,242,880
    const size_t PB_S = (size_t)4 * LEN * 2;    // s1/s2 bf16:          524,288 each
    const size_t PB_P = (size_t)4 * LEN * 4;    // partials fp32:     1,048,576... (2 halves x 2 outs)
    const size_t PERB = PB_Y + 2 * PB_S + (size_t)2 * 2 * LEN * 4;  // 8,388,608
    size_t avail = (ws_size > HEAD) ? (ws_size - HEAD) : 0;
    int nb = (int)(avail / PERB);
    if (nb > 32) nb = 32;
    if (nb < 1) nb = 1;

    bf16*  y    = (bf16*)rest;
    bf16*  s1   = (bf16*)(rest + PB_Y * (size_t)nb);
    bf16*  s2   = (bf16*)(rest + (PB_Y + PB_S) * (size_t)nb);
    float* part = (float*)(rest + (PB_Y + 2 * PB_S) * (size_t)nb);

    hipLaunchKernelGGL(k_prep,     dim3(3200), dim3(256), 0, stream, w_eff, fragA_eff);
    hipLaunchKernelGGL(k_prep_fft, dim3(448),  dim3(256), 0, stream, w_fft, fragA_fft);
    hipLaunchKernelGGL(k_prep_mot, dim3(960),  dim3(256), 0, stream, w_motif, fragA_mot);
    hipLaunchKernelGGL(k_x2b,      dim3(4096), dim3(256), 0, stream, x, xb,
                       (int)(32 * 4 * LEN / 8));

    for (int b0 = 0; b0 < 32; b0 += nb) {
        int nbb = (32 - b0 < nb) ? (32 - b0) : nb;
        hipLaunchKernelGGL(k_motif_mfma, dim3(16, nbb, 10), dim3(256), 0, stream,
                           xb, fragA_mot, b_motif, y, b0);
        hipLaunchKernelGGL(k_reduce, dim3(32, nbb), dim3(256), 0, stream,
                           (const short*)y, w_reduce, b_reduce, s1);
        hipLaunchKernelGGL(k_fft, dim3(16, nbb), dim3(256), 0, stream,
                           (const short*)s1, fragA_fft, b_fft, s2);
        hipLaunchKernelGGL(k_effect, dim3(32, nbb, 2), dim3(256), 0, stream,
                           (const short*)y, (const short*)s2, fragA_eff,
                           w_expand, b_expand, part);
        hipLaunchKernelGGL(k_comb, dim3(64, nbb), dim3(256), 0, stream,
                           part, b_eff, out, b0);
    }
}

// Round 12
// 435.549 us; speedup vs baseline: 5.2137x; 1.0413x over previous
//
#include <hip/hip_runtime.h>
#include <hip/hip_bf16.h>
#include <math.h>

#define LEN 65536
#define LOUT 64536
typedef __hip_bfloat16 bf16;
typedef __attribute__((ext_vector_type(8))) short short8;
typedef __attribute__((ext_vector_type(4))) float f32x4;

__device__ inline float b2f(bf16 h) { return __bfloat162float(h); }
__device__ inline bf16 f2b(float f) { return __float2bfloat16(f); }
__device__ inline float us2f(unsigned short u) { bf16 h = *(bf16*)&u; return __bfloat162float(h); }
// cheap softplus: max(v,0) + log(1+exp(-|v|)), hw exp/log
__device__ inline float softplus_f(float v) {
    return fmaxf(v, 0.f) + __logf(1.f + __expf(-fabsf(v)));
}

// ============ Kernel 0: convert x fp32 -> bf16 (whole tensor, one pass) ============
__global__ __launch_bounds__(256) void k_x2b(const float* __restrict__ x,
                                             short* __restrict__ xb, int n8) {
    int i = blockIdx.x * 256 + threadIdx.x;
    if (i >= n8) return;
    const float* src = x + (size_t)i * 8;
    float4 f0 = *(const float4*)src;
    float4 f1 = *(const float4*)(src + 4);
    short8 v; bf16 h;
    h = f2b(f0.x); v[0] = *(short*)&h;
    h = f2b(f0.y); v[1] = *(short*)&h;
    h = f2b(f0.z); v[2] = *(short*)&h;
    h = f2b(f0.w); v[3] = *(short*)&h;
    h = f2b(f1.x); v[4] = *(short*)&h;
    h = f2b(f1.y); v[5] = *(short*)&h;
    h = f2b(f1.z); v[6] = *(short*)&h;
    h = f2b(f1.w); v[7] = *(short*)&h;
    *(short8*)(xb + (size_t)i * 8) = v;
}

// ============ prep: motif-conv A-fragments (shift trick + align-shift 7) ============
__global__ __launch_bounds__(256) void k_prep_mot(const float* __restrict__ w_motif,
                                                  short* __restrict__ fragA) {
    int idx = blockIdx.x * 256 + threadIdx.x;
    if (idx >= 40 * 4 * 3 * 64 * 8) return;
    int i = idx & 7;
    int lane = (idx >> 3) & 63;
    int rest = idx >> 9;
    int qc = rest % 3; rest /= 3;
    int c = rest & 3; int o = rest >> 2;
    int dlt = lane & 15, kb = lane >> 4;
    int m = 32 * qc + 8 * kb + i;
    int k = m - 7 - dlt;
    float v = (k >= 0 && k < 51) ? w_motif[(o * 4 + c) * 51 + k] : 0.f;
    bf16 h = f2b(v);
    fragA[idx] = *(short*)&h;
}

// ============ Kernel 1: motif conv (4->40, K=51, pad25) + softplus via bf16 MFMA ============
#define MOT_BLKS 522
#define MOT_PAD  528
__global__ __launch_bounds__(256, 2) void k_motif_mfma(const short* __restrict__ xb,
        const short* __restrict__ fragA, const float* __restrict__ b_motif,
        bf16* __restrict__ y, int b0) {
    __shared__ __align__(16) short bwin[4][MOT_PAD * 8];   // 33,792 B
    const int tid = threadIdx.x;
    const int lane = tid & 63, wv = tid >> 6;
    const int wg = blockIdx.x, bl = blockIdx.y, og = blockIdx.z;
    const int bg = b0 + bl;
    const int L0 = wg * 4096;
    const int win0 = L0 - 32;
    const int ln15 = lane & 15, lkb = lane >> 4;

    short8 af[4][12];
    #pragma unroll
    for (int Mt = 0; Mt < 4; ++Mt)
        #pragma unroll
        for (int kq = 0; kq < 12; ++kq)
            af[Mt][kq] = *(const short8*)(fragA +
                (size_t)(((og * 4 + Mt) * 12 + kq) * 64 + lane) * 8);

    #pragma unroll 1
    for (int c = 0; c < 4; ++c) {
        const short* src = xb + ((size_t)bg * 4 + c) * LEN;
        for (int Lb = tid; Lb < MOT_BLKS; Lb += 256) {
            int gi = win0 + Lb * 8;
            short8 v;
            if (gi >= 0 && gi + 8 <= LEN) {
                v = *(const short8*)(src + gi);
            } else {
                #pragma unroll
                for (int j = 0; j < 8; ++j)
                    v[j] = (gi + j >= 0 && gi + j < LEN) ? src[gi + j] : (short)0;
            }
            int Pb = Lb ^ ((Lb >> 3) & 7);
            *(short8*)(&bwin[c][Pb * 8]) = v;
        }
    }
    __syncthreads();

    #pragma unroll 1
    for (int nt = 0; nt < 4; ++nt) {
        const int tt = wv * 4 + nt;
        f32x4 acc[4];
        #pragma unroll
        for (int Mt = 0; Mt < 4; ++Mt) acc[Mt] = (f32x4){0.f, 0.f, 0.f, 0.f};
        #pragma unroll
        for (int c = 0; c < 4; ++c) {
            #pragma unroll
            for (int qc = 0; qc < 3; ++qc) {
                int L = 32 * tt + 2 * ln15 + 4 * qc + lkb;
                int P = L ^ ((L >> 3) & 7);
                short8 bfr = *(const short8*)(&bwin[c][P * 8]);
                #pragma unroll
                for (int Mt = 0; Mt < 4; ++Mt)
                    acc[Mt] = __builtin_amdgcn_mfma_f32_16x16x32_bf16(
                        af[Mt][c * 3 + qc], bfr, acc[Mt], 0, 0, 0);
            }
        }
        #pragma unroll
        for (int Mt = 0; Mt < 4; ++Mt) {
            float bb = b_motif[og * 4 + Mt];
            int pos = L0 + tt * 256 + 16 * ln15 + 4 * lkb;
            ushort4 st; bf16 h;
            float v0 = softplus_f(acc[Mt][0] + bb);
            float v1 = softplus_f(acc[Mt][1] + bb);
            float v2 = softplus_f(acc[Mt][2] + bb);
            float v3 = softplus_f(acc[Mt][3] + bb);
            h = f2b(v0); st.x = *(unsigned short*)&h;
            h = f2b(v1); st.y = *(unsigned short*)&h;
            h = f2b(v2); st.z = *(unsigned short*)&h;
            h = f2b(v3); st.w = *(unsigned short*)&h;
            *(ushort4*)(&y[((size_t)bl * 40 + og * 4 + Mt) * LEN + pos]) = st;
        }
    }
}

// ============ Kernel 1b: reduce (40->4, 1x1) from y ============
__global__ __launch_bounds__(256) void k_reduce(const short* __restrict__ y,
        const float* __restrict__ w_reduce, const float* __restrict__ b_reduce,
        bf16* __restrict__ s1) {
    const int tid = threadIdx.x;
    const int bl = blockIdx.y;
    const int l8 = (blockIdx.x * 256 + tid) * 8;
    float s[4][8];
    #pragma unroll
    for (int c = 0; c < 4; ++c)
        #pragma unroll
        for (int e = 0; e < 8; ++e) s[c][e] = b_reduce[c];
    #pragma unroll 1
    for (int o = 0; o < 40; ++o) {
        short8 v = *(const short8*)(y + ((size_t)bl * 40 + o) * LEN + l8);
        float yv[8];
        #pragma unroll
        for (int e = 0; e < 8; ++e) yv[e] = us2f((unsigned short)v[e]);
        #pragma unroll
        for (int c = 0; c < 4; ++c) {
            float w = w_reduce[c * 40 + o];
            #pragma unroll
            for (int e = 0; e < 8; ++e) s[c][e] += w * yv[e];
        }
    }
    #pragma unroll
    for (int c = 0; c < 4; ++c) {
        short8 st; bf16 h;
        #pragma unroll
        for (int e = 0; e < 8; ++e) { h = f2b(s[c][e]); st[e] = *(short*)&h; }
        *(short8*)(&s1[((size_t)bl * 4 + c) * LEN + l8]) = st;
    }
}

// ============ prep: fft-conv A-fragments ============
__global__ __launch_bounds__(256) void k_prep_fft(const float* __restrict__ w_fft,
                                                  short* __restrict__ fragA) {
    int idx = blockIdx.x * 256 + threadIdx.x;
    if (idx >= 4 * 7 * 4 * 2 * 64 * 8) return;
    int i = idx & 7;
    int lane = (idx >> 3) & 63;
    int rest = idx >> 9;
    int ql = rest & 1; rest >>= 1;
    int Mt = rest & 3; rest >>= 2;
    int qb = rest % 7; int c = rest / 7;
    int dlt = lane & 15, kb = lane >> 4;
    int kkp = 32 * (qb * 2 + ql) + 8 * kb + i;
    int kk = kkp - dlt;
    float v = (kk >= 0 && kk < 401) ? w_fft[(Mt * 4 + c) * 401 + kk] : 0.f;
    bf16 h = f2b(v);
    fragA[idx] = *(short*)&h;
}

// ============ Kernel 2: fft conv (4->4, K=401, pad 200) via bf16 MFMA ============
#define FFT_BLKS 568
__global__ __launch_bounds__(256) void k_fft(const short* __restrict__ s1,
        const short* __restrict__ fragA, const float* __restrict__ b_fft,
        bf16* __restrict__ s2) {
    __shared__ __align__(16) short bwin[4][FFT_BLKS * 8];   // 36,352 B
    const int tid = threadIdx.x;
    const int lane = tid & 63, wv = tid >> 6;
    const int wg = blockIdx.x, bl = blockIdx.y;
    const int P0 = wg * 4096;
    const int win0 = P0 - 200;
    const int ln15 = lane & 15, lkb = lane >> 4;

    f32x4 acc[4][4];
    #pragma unroll
    for (int Mt = 0; Mt < 4; ++Mt)
        #pragma unroll
        for (int nt = 0; nt < 4; ++nt)
            acc[Mt][nt] = (f32x4){0.f, 0.f, 0.f, 0.f};

    #pragma unroll 1
    for (int cl = 0; cl < 4; ++cl) {
        const short* src = s1 + ((size_t)bl * 4 + cl) * LEN;
        for (int Lb = tid; Lb < FFT_BLKS; Lb += 256) {
            int gi = win0 + Lb * 8;
            short8 v;
            if (gi >= 0 && gi + 8 <= LEN) {
                v = *(const short8*)(src + gi);
            } else {
                #pragma unroll
                for (int j = 0; j < 8; ++j)
                    v[j] = (gi + j >= 0 && gi + j < LEN) ? src[gi + j] : (short)0;
            }
            int Pb = Lb ^ ((Lb >> 3) & 7);
            *(short8*)(&bwin[cl][Pb * 8]) = v;
        }
    }
    __syncthreads();

    #pragma unroll 1
    for (int cl = 0; cl < 4; ++cl) {
        #pragma unroll 1
        for (int qb = 0; qb < 7; ++qb) {
            short8 af[4][2];
            #pragma unroll
            for (int Mt = 0; Mt < 4; ++Mt)
                #pragma unroll
                for (int ql = 0; ql < 2; ++ql)
                    af[Mt][ql] = *(const short8*)(fragA +
                        (size_t)((((cl * 7 + qb) * 4 + Mt) * 2 + ql) * 64 + lane) * 8);
            #pragma unroll
            for (int nt = 0; nt < 4; ++nt) {
                const int tt = wv * 4 + nt;
                #pragma unroll
                for (int ql = 0; ql < 2; ++ql) {
                    int qc = qb * 2 + ql;
                    int L = 2 * ln15 + lkb + 4 * qc + 32 * tt;
                    int P = L ^ ((L >> 3) & 7);
                    short8 bfr = *(const short8*)(&bwin[cl][P * 8]);
                    #pragma unroll
                    for (int Mt = 0; Mt < 4; ++Mt)
                        acc[Mt][nt] = __builtin_amdgcn_mfma_f32_16x16x32_bf16(
                            af[Mt][ql], bfr, acc[Mt][nt], 0, 0, 0);
                }
            }
        }
    }

    #pragma unroll
    for (int Mt = 0; Mt < 4; ++Mt) {
        float bb = b_fft[Mt];
        #pragma unroll
        for (int nt = 0; nt < 4; ++nt) {
            int tt = wv * 4 + nt;
            int pos = P0 + tt * 256 + 16 * ln15 + 4 * lkb;
            ushort4 st; bf16 h;
            h = f2b(acc[Mt][nt][0] + bb); st.x = *(unsigned short*)&h;
            h = f2b(acc[Mt][nt][1] + bb); st.y = *(unsigned short*)&h;
            h = f2b(acc[Mt][nt][2] + bb); st.z = *(unsigned short*)&h;
            h = f2b(acc[Mt][nt][3] + bb); st.w = *(unsigned short*)&h;
            *(ushort4*)(&s2[((size_t)bl * 4 + Mt) * LEN + pos]) = st;
        }
    }
}

// ============ prep: effect-conv A-fragments ============
__global__ __launch_bounds__(256) void k_prep(const float* __restrict__ w_eff,
                                              short* __restrict__ fragA) {
    int idx = blockIdx.x * 256 + threadIdx.x;
    if (idx >= 40 * 4 * 2 * 5 * 64 * 8) return;
    int i = idx & 7;
    int lane = (idx >> 3) & 63;
    int rest = idx >> 9;
    int ql = rest % 5; rest /= 5;
    int Mt = rest & 1; rest >>= 1;
    int qb = rest & 3; int c = rest >> 2;
    int q = qb * 5 + ql;
    int dlt = lane & 15, kb = lane >> 4;
    int kp = 32 * q + 8 * kb + i;
    int kk = kp - dlt;
    float v = (kk >= 0 && kk < 601) ? w_eff[(Mt * 40 + c) * 601 + kk] : 0.f;
    bf16 h = __float2bfloat16(v);
    fragA[idx] = *(short*)&h;
}

// ============ Kernel 4: effect conv (40->2, K=601) + FUSED gate, partials ============
// Channel split across blockIdx.z (2 halves x 20 ch = 5 chunks), wave-split K.
// v5 gate restructure: positions OUTER, channels INNER — s2win read/converted ONCE
// per position block (was 4x), y-prefetch regs yreg[2][4] per (posblock, channel).
#define EFF_NBLK 336
#define EFF_SH (EFF_NBLK * 8)      // shorts per channel window
__device__ __forceinline__ void eff_prefetch(const short* __restrict__ mact,
        size_t chanBase, int cc, int tid, int win0, short8 (&yreg)[2][4]) {
    #pragma unroll
    for (int it = 0; it < 2; ++it) {
        int Lb = tid + it * 256;
        if (Lb < EFF_NBLK) {
            int gi = win0 + Lb * 8;
            bool full = (gi + 8 <= LEN);
            #pragma unroll
            for (int ch = 0; ch < 4; ++ch) {
                const short* src = mact + (chanBase + cc * 4 + ch) * (size_t)LEN;
                short8 v = {0, 0, 0, 0, 0, 0, 0, 0};
                if (full) {
                    v = *(const short8*)(src + gi);
                } else {
                    #pragma unroll
                    for (int j = 0; j < 8; ++j)
                        v[j] = (gi + j < LEN) ? src[gi + j] : (short)0;
                }
                yreg[it][ch] = v;
            }
        }
    }
}

__global__ __launch_bounds__(256, 3) void k_effect(const short* __restrict__ mact,
        const short* __restrict__ s2,
        const short* __restrict__ fragA,
        const float* __restrict__ w_expand, const float* __restrict__ b_expand,
        float* __restrict__ part) {
    // carved shared block: bwin | s2win | wexp | bexp ; reduction reuses bwin+s2win
    __shared__ __align__(16) char smem[2 * EFF_SH * 4 * 2 + 160 * 4 + 40 * 4];
    short (*bwin)[EFF_SH]  = (short(*)[EFF_SH])smem;
    short (*s2win)[EFF_SH] = (short(*)[EFF_SH])(smem + EFF_SH * 4 * 2);
    float* wexp = (float*)(smem + 2 * EFF_SH * 4 * 2);
    float* bexp = wexp + 160;
    float* red  = (float*)smem;   // 32 KB scratch, used after cc loop

    const int tid = threadIdx.x;
    const int lane = tid & 63, wv = tid >> 6;
    const int wgl = blockIdx.x, bl = blockIdx.y, half = blockIdx.z;
    const int coff = half * 20;          // channel offset of this half
    const int L0 = wgl * 2048;
    const int win0 = L0 + 200;
    const int ln15 = lane & 15, lkb = lane >> 4;
    const size_t chanBase = (size_t)bl * 40 + coff;

    // stage expand weights + s2 window ONCE (consumed after loop-top barrier)
    if (tid < 160) wexp[tid] = w_expand[tid];
    if (tid < 40) bexp[tid] = b_expand[tid];
    #pragma unroll 1
    for (int c = 0; c < 4; ++c) {
        const short* sp = s2 + ((size_t)bl * 4 + c) * LEN;
        for (int Lb = tid; Lb < EFF_NBLK; Lb += 256) {
            int gi = win0 + Lb * 8;
            short8 v = {0, 0, 0, 0, 0, 0, 0, 0};
            if (gi + 8 <= LEN) {
                v = *(const short8*)(sp + gi);
            } else {
                #pragma unroll
                for (int j = 0; j < 8; ++j)
                    v[j] = (gi + j < LEN) ? sp[gi + j] : (short)0;
            }
            *(short8*)(&s2win[c][Lb * 8]) = v;
        }
    }

    f32x4 acc[2][8];   // [Mt][tt] — this wave's partial (its channel slice)
    #pragma unroll
    for (int Mt = 0; Mt < 2; ++Mt)
        #pragma unroll
        for (int tt = 0; tt < 8; ++tt)
            acc[Mt][tt] = (f32x4){0.f, 0.f, 0.f, 0.f};

    short8 yreg[2][4];
    eff_prefetch(mact, chanBase, 0, tid, win0, yreg);

    #pragma unroll 1
    for (int cc = 0; cc < 5; ++cc) {
        __syncthreads();
        // ---- write phase: positions outer, channels inner (s2v read once) ----
        #pragma unroll
        for (int it = 0; it < 2; ++it) {
            int Lb = tid + it * 256;
            if (Lb < EFF_NBLK) {
                float s2v[4][8];
                #pragma unroll
                for (int c = 0; c < 4; ++c) {
                    short8 sv = *(const short8*)(&s2win[c][Lb * 8]);
                    #pragma unroll
                    for (int j = 0; j < 8; ++j) s2v[c][j] = us2f((unsigned short)sv[j]);
                }
                int P = Lb ^ ((Lb >> 3) & 7);
                #pragma unroll
                for (int ch = 0; ch < 4; ++ch) {
                    int o = coff + cc * 4 + ch;
                    float w0 = wexp[o * 4 + 0], w1 = wexp[o * 4 + 1];
                    float w2 = wexp[o * 4 + 2], w3 = wexp[o * 4 + 3];
                    float be = bexp[o];
                    short8 w;
                    #pragma unroll
                    for (int j = 0; j < 8; ++j) {
                        float sg = be + w0 * s2v[0][j] + w1 * s2v[1][j]
                                      + w2 * s2v[2][j] + w3 * s2v[3][j];
                        float g = __builtin_amdgcn_rcpf(1.f + __expf(-sg));
                        float yv = us2f((unsigned short)yreg[it][ch][j]) * g;
                        bf16 h = f2b(yv);
                        w[j] = *(short*)&h;
                    }
                    *(short8*)(&bwin[ch][P * 8]) = w;
                }
            }
        }
        __syncthreads();
        // ---- T14: issue next chunk's y loads (land during compute) ----
        if (cc < 4) eff_prefetch(mact, chanBase, cc + 1, tid, win0, yreg);
        // ---- compute phase: this wave's channel only (cl = wv) ----
        const int cg = coff + cc * 4 + wv;
        #pragma unroll 1
        for (int qb = 0; qb < 4; ++qb) {
            short8 af[2][5];
            #pragma unroll
            for (int Mt = 0; Mt < 2; ++Mt)
                #pragma unroll
                for (int ql = 0; ql < 5; ++ql)
                    af[Mt][ql] = *(const short8*)(fragA +
                        (size_t)(((((cg * 4 + qb) * 2 + Mt) * 5 + ql) * 64 + lane) * 8));
            #pragma unroll
            for (int tt = 0; tt < 8; ++tt) {
                #pragma unroll
                for (int ql = 0; ql < 5; ++ql) {
                    int q = qb * 5 + ql;
                    int L = 32 * tt + 2 * ln15 + 4 * q + lkb;
                    int P = L ^ ((L >> 3) & 7);
                    short8 bfr = *(const short8*)(&bwin[wv][P * 8]);
                    acc[0][tt] = __builtin_amdgcn_mfma_f32_16x16x32_bf16(
                        af[0][ql], bfr, acc[0][tt], 0, 0, 0);
                    acc[1][tt] = __builtin_amdgcn_mfma_f32_16x16x32_bf16(
                        af[1][ql], bfr, acc[1][tt], 0, 0, 0);
                }
            }
        }
    }

    // ---- cross-wave reduction: acc_total = sum over waves (bwin/s2win dead) ----
    __syncthreads();
    if (wv == 1 || wv == 3) {
        float* p = red + (wv >> 1) * 4096;
        #pragma unroll
        for (int Mt = 0; Mt < 2; ++Mt)
            #pragma unroll
            for (int tt = 0; tt < 8; ++tt)
                *(f32x4*)(p + (Mt * 8 + tt) * 256 + lane * 4) = acc[Mt][tt];
    }
    __syncthreads();
    if (wv == 0 || wv == 2) {
        float* p = red + (wv >> 1) * 4096;
        #pragma unroll
        for (int Mt = 0; Mt < 2; ++Mt)
            #pragma unroll
            for (int tt = 0; tt < 8; ++tt)
                acc[Mt][tt] += *(const f32x4*)(p + (Mt * 8 + tt) * 256 + lane * 4);
    }
    __syncthreads();
    if (wv == 2) {
        #pragma unroll
        for (int Mt = 0; Mt < 2; ++Mt)
            #pragma unroll
            for (int tt = 0; tt < 8; ++tt)
                *(f32x4*)(red + (Mt * 8 + tt) * 256 + lane * 4) = acc[Mt][tt];
    }
    __syncthreads();
    if (wv == 0) {
        // write fp32 partial (no bias/sigmoid) to part[bl][half][Mt][pos]
        #pragma unroll
        for (int Mt = 0; Mt < 2; ++Mt) {
            #pragma unroll
            for (int tt = 0; tt < 8; ++tt) {
                f32x4 a = acc[Mt][tt];
                a += *(const f32x4*)(red + (Mt * 8 + tt) * 256 + lane * 4);
                int pos = L0 + tt * 256 + 16 * ln15 + 4 * lkb;
                float4 st; st.x = a[0]; st.y = a[1]; st.z = a[2]; st.w = a[3];
                *(float4*)(&part[(((size_t)bl * 2 + half) * 2 + Mt) * LEN + pos]) = st;
            }
        }
    }
}

// ============ Kernel 5: combine partials + bias + sigmoid -> out ============
__global__ __launch_bounds__(256) void k_comb(const float* __restrict__ part,
        const float* __restrict__ b_eff, float* __restrict__ out, int b0) {
    const int tid = threadIdx.x;
    const int bl = blockIdx.y, bg = b0 + bl;
    int l4 = (blockIdx.x * 256 + tid) * 4;
    if (l4 >= LOUT) return;
    #pragma unroll
    for (int Mt = 0; Mt < 2; ++Mt) {
        float bb = b_eff[Mt];
        float4 p0 = *(const float4*)(&part[(((size_t)bl * 2 + 0) * 2 + Mt) * LEN + l4]);
        float4 p1 = *(const float4*)(&part[(((size_t)bl * 2 + 1) * 2 + Mt) * LEN + l4]);
        float4 st;
        st.x = __builtin_amdgcn_rcpf(1.f + __expf(-(p0.x + p1.x + bb)));
        st.y = __builtin_amdgcn_rcpf(1.f + __expf(-(p0.y + p1.y + bb)));
        st.z = __builtin_amdgcn_rcpf(1.f + __expf(-(p0.z + p1.z + bb)));
        st.w = __builtin_amdgcn_rcpf(1.f + __expf(-(p0.w + p1.w + bb)));
        *(float4*)(&out[((size_t)bg * 2 + Mt) * LOUT + l4]) = st;
    }
}

extern "C" void kernel_launch(void* const* d_in, const int* in_sizes, int n_in,
                              void* d_out, int out_size, void* d_ws, size_t ws_size,
                              hipStream_t stream) {
    const float* x        = (const float*)d_in[0];
    const float* w_motif  = (const float*)d_in[1];
    const float* b_motif  = (const float*)d_in[2];
    const float* w_reduce = (const float*)d_in[3];
    const float* b_reduce = (const float*)d_in[4];
    const float* w_fft    = (const float*)d_in[5];
    const float* b_fft    = (const float*)d_in[6];
    const float* w_expand = (const float*)d_in[7];
    const float* b_expand = (const float*)d_in[8];
    const float* w_eff    = (const float*)d_in[9];
    const float* b_eff    = (const float*)d_in[10];
    float* out = (float*)d_out;

    const size_t FRAGA_EFF = (size_t)40 * 4 * 2 * 5 * 64 * 8 * 2;  // 1,638,400
    const size_t FRAGA_FFT = (size_t)4 * 7 * 4 * 2 * 64 * 8 * 2;   //   229,376
    const size_t FRAGA_MOT = (size_t)40 * 4 * 3 * 64 * 8 * 2;      //   491,520
    const size_t XB_B      = (size_t)32 * 4 * LEN * 2;             // 16,777,216
    const size_t HEAD = FRAGA_EFF + FRAGA_FFT + FRAGA_MOT + XB_B;

    short* fragA_eff = (short*)d_ws;
    short* fragA_fft = (short*)((char*)d_ws + FRAGA_EFF);
    short* fragA_mot = (short*)((char*)d_ws + FRAGA_EFF + FRAGA_FFT);
    short* xb        = (short*)((char*)d_ws + FRAGA_EFF + FRAGA_FFT + FRAGA_MOT);
    char*  rest      = (char*)d_ws + HEAD;

    const size_t PB_Y = (size_t)40 * LEN * 2;   // y bf16
    const size_t PB_S = (size_t)4 * LEN * 2;    // s1/s2 bf16
    const size_t PERB = PB_Y + 2 * PB_S + (size_t)2 * 2 * LEN * 4;  // + fp32 partials
    size_t avail = (ws_size > HEAD) ? (ws_size - HEAD) : 0;
    int nb = (int)(avail / PERB);
    if (nb > 32) nb = 32;
    if (nb < 1) nb = 1;

    bf16*  y    = (bf16*)rest;
    bf16*  s1   = (bf16*)(rest + PB_Y * (size_t)nb);
    bf16*  s2   = (bf16*)(rest + (PB_Y + PB_S) * (size_t)nb);
    float* part = (float*)(rest + (PB_Y + 2 * PB_S) * (size_t)nb);

    hipLaunchKernelGGL(k_prep,     dim3(3200), dim3(256), 0, stream, w_eff, fragA_eff);
    hipLaunchKernelGGL(k_prep_fft, dim3(448),  dim3(256), 0, stream, w_fft, fragA_fft);
    hipLaunchKernelGGL(k_prep_mot, dim3(960),  dim3(256), 0, stream, w_motif, fragA_mot);
    hipLaunchKernelGGL(k_x2b,      dim3(4096), dim3(256), 0, stream, x, xb,
                       (int)(32 * 4 * LEN / 8));

    for (int b0 = 0; b0 < 32; b0 += nb) {
        int nbb = (32 - b0 < nb) ? (32 - b0) : nb;
        hipLaunchKernelGGL(k_motif_mfma, dim3(16, nbb, 10), dim3(256), 0, stream,
                           xb, fragA_mot, b_motif, y, b0);
        hipLaunchKernelGGL(k_reduce, dim3(32, nbb), dim3(256), 0, stream,
                           (const short*)y, w_reduce, b_reduce, s1);
        hipLaunchKernelGGL(k_fft, dim3(16, nbb), dim3(256), 0, stream,
                           (const short*)s1, fragA_fft, b_fft, s2);
        hipLaunchKernelGGL(k_effect, dim3(32, nbb, 2), dim3(256), 0, stream,
                           (const short*)y, (const short*)s2, fragA_eff,
                           w_expand, b_expand, part);
        hipLaunchKernelGGL(k_comb, dim3(64, nbb), dim3(256), 0, stream,
                           part, b_eff, out, b0);
    }
}

// Round 13
// 392.595 us; speedup vs baseline: 5.7841x; 1.1094x over previous
//
#include <hip/hip_runtime.h>
#include <hip/hip_bf16.h>
#include <math.h>

#define LEN 65536
#define LOUT 64536
typedef __hip_bfloat16 bf16;
typedef __attribute__((ext_vector_type(8))) short short8;
typedef __attribute__((ext_vector_type(4))) float f32x4;

__device__ inline float b2f(bf16 h) { return __bfloat162float(h); }
__device__ inline bf16 f2b(float f) { return __float2bfloat16(f); }
__device__ inline float us2f(unsigned short u) { bf16 h = *(bf16*)&u; return __bfloat162float(h); }
// cheap softplus: max(v,0) + log(1+exp(-|v|)), hw exp/log
__device__ inline float softplus_f(float v) {
    return fmaxf(v, 0.f) + __logf(1.f + __expf(-fabsf(v)));
}

// ============ Kernel 0: convert x fp32 -> bf16 (whole tensor, one pass) ============
__global__ __launch_bounds__(256) void k_x2b(const float* __restrict__ x,
                                             short* __restrict__ xb, int n8) {
    int i = blockIdx.x * 256 + threadIdx.x;
    if (i >= n8) return;
    const float* src = x + (size_t)i * 8;
    float4 f0 = *(const float4*)src;
    float4 f1 = *(const float4*)(src + 4);
    short8 v; bf16 h;
    h = f2b(f0.x); v[0] = *(short*)&h;
    h = f2b(f0.y); v[1] = *(short*)&h;
    h = f2b(f0.z); v[2] = *(short*)&h;
    h = f2b(f0.w); v[3] = *(short*)&h;
    h = f2b(f1.x); v[4] = *(short*)&h;
    h = f2b(f1.y); v[5] = *(short*)&h;
    h = f2b(f1.z); v[6] = *(short*)&h;
    h = f2b(f1.w); v[7] = *(short*)&h;
    *(short8*)(xb + (size_t)i * 8) = v;
}

// ============ prep: motif-conv A-fragments (shift trick + align-shift 7) ============
__global__ __launch_bounds__(256) void k_prep_mot(const float* __restrict__ w_motif,
                                                  short* __restrict__ fragA) {
    int idx = blockIdx.x * 256 + threadIdx.x;
    if (idx >= 40 * 4 * 3 * 64 * 8) return;
    int i = idx & 7;
    int lane = (idx >> 3) & 63;
    int rest = idx >> 9;
    int qc = rest % 3; rest /= 3;
    int c = rest & 3; int o = rest >> 2;
    int dlt = lane & 15, kb = lane >> 4;
    int m = 32 * qc + 8 * kb + i;
    int k = m - 7 - dlt;
    float v = (k >= 0 && k < 51) ? w_motif[(o * 4 + c) * 51 + k] : 0.f;
    bf16 h = f2b(v);
    fragA[idx] = *(short*)&h;
}

// ============ Kernel 1: motif conv (4->40) + softplus + FUSED reduce (40->4) ============
// Single pass per tile: stage xb once, loop 10 o-groups streaming A-frags from L2,
// accumulate s1[c] = b_c + sum_o w[c][o]*softplus(...) in registers. No k_reduce pass.
#define MOT_BLKS 522
#define MOT_PAD  528
__global__ __launch_bounds__(256, 2) void k_motif_mfma(const short* __restrict__ xb,
        const short* __restrict__ fragA, const float* __restrict__ b_motif,
        const float* __restrict__ w_reduce, const float* __restrict__ b_reduce,
        bf16* __restrict__ y, bf16* __restrict__ s1, int b0) {
    __shared__ __align__(16) short bwin[4][MOT_PAD * 8];   // 33,792 B
    const int tid = threadIdx.x;
    const int lane = tid & 63, wv = tid >> 6;
    const int wg = blockIdx.x, bl = blockIdx.y;
    const int bg = b0 + bl;
    const int L0 = wg * 4096;
    const int win0 = L0 - 32;
    const int ln15 = lane & 15, lkb = lane >> 4;

    // stage bf16 x window into swizzled LDS (once per WG)
    #pragma unroll 1
    for (int c = 0; c < 4; ++c) {
        const short* src = xb + ((size_t)bg * 4 + c) * LEN;
        for (int Lb = tid; Lb < MOT_BLKS; Lb += 256) {
            int gi = win0 + Lb * 8;
            short8 v;
            if (gi >= 0 && gi + 8 <= LEN) {
                v = *(const short8*)(src + gi);
            } else {
                #pragma unroll
                for (int j = 0; j < 8; ++j)
                    v[j] = (gi + j >= 0 && gi + j < LEN) ? src[gi + j] : (short)0;
            }
            int Pb = Lb ^ ((Lb >> 3) & 7);
            *(short8*)(&bwin[c][Pb * 8]) = v;
        }
    }
    __syncthreads();

    // s1 accumulators [nt][c][j], init with bias
    float s1a[4][4][4];
    #pragma unroll
    for (int nt = 0; nt < 4; ++nt)
        #pragma unroll
        for (int c = 0; c < 4; ++c) {
            float bc = b_reduce[c];
            #pragma unroll
            for (int j = 0; j < 4; ++j) s1a[nt][c][j] = bc;
        }

    #pragma unroll 1
    for (int og = 0; og < 10; ++og) {
        f32x4 acc[4][4];   // [Mt][nt]
        #pragma unroll
        for (int Mt = 0; Mt < 4; ++Mt)
            #pragma unroll
            for (int nt = 0; nt < 4; ++nt)
                acc[Mt][nt] = (f32x4){0.f, 0.f, 0.f, 0.f};

        #pragma unroll 1
        for (int c = 0; c < 4; ++c) {
            short8 afc[4][3];  // [Mt][qc]
            #pragma unroll
            for (int Mt = 0; Mt < 4; ++Mt)
                #pragma unroll
                for (int qc = 0; qc < 3; ++qc)
                    afc[Mt][qc] = *(const short8*)(fragA +
                        (size_t)(((og * 4 + Mt) * 12 + c * 3 + qc) * 64 + lane) * 8);
            #pragma unroll
            for (int nt = 0; nt < 4; ++nt) {
                const int tt = wv * 4 + nt;
                #pragma unroll
                for (int qc = 0; qc < 3; ++qc) {
                    int L = 32 * tt + 2 * ln15 + 4 * qc + lkb;
                    int P = L ^ ((L >> 3) & 7);
                    short8 bfr = *(const short8*)(&bwin[c][P * 8]);
                    #pragma unroll
                    for (int Mt = 0; Mt < 4; ++Mt)
                        acc[Mt][nt] = __builtin_amdgcn_mfma_f32_16x16x32_bf16(
                            afc[Mt][qc], bfr, acc[Mt][nt], 0, 0, 0);
                }
            }
        }

        // epilogue for this o-group: softplus -> y, accumulate s1
        #pragma unroll
        for (int Mt = 0; Mt < 4; ++Mt) {
            const int o = og * 4 + Mt;
            const float bb = b_motif[o];
            const float wr0 = w_reduce[0 * 40 + o], wr1 = w_reduce[1 * 40 + o];
            const float wr2 = w_reduce[2 * 40 + o], wr3 = w_reduce[3 * 40 + o];
            #pragma unroll
            for (int nt = 0; nt < 4; ++nt) {
                int tt = wv * 4 + nt;
                int pos = L0 + tt * 256 + 16 * ln15 + 4 * lkb;
                float v0 = softplus_f(acc[Mt][nt][0] + bb);
                float v1 = softplus_f(acc[Mt][nt][1] + bb);
                float v2 = softplus_f(acc[Mt][nt][2] + bb);
                float v3 = softplus_f(acc[Mt][nt][3] + bb);
                ushort4 st; bf16 h;
                h = f2b(v0); st.x = *(unsigned short*)&h;
                h = f2b(v1); st.y = *(unsigned short*)&h;
                h = f2b(v2); st.z = *(unsigned short*)&h;
                h = f2b(v3); st.w = *(unsigned short*)&h;
                *(ushort4*)(&y[((size_t)bl * 40 + o) * LEN + pos]) = st;
                s1a[nt][0][0] += wr0 * v0; s1a[nt][0][1] += wr0 * v1;
                s1a[nt][0][2] += wr0 * v2; s1a[nt][0][3] += wr0 * v3;
                s1a[nt][1][0] += wr1 * v0; s1a[nt][1][1] += wr1 * v1;
                s1a[nt][1][2] += wr1 * v2; s1a[nt][1][3] += wr1 * v3;
                s1a[nt][2][0] += wr2 * v0; s1a[nt][2][1] += wr2 * v1;
                s1a[nt][2][2] += wr2 * v2; s1a[nt][2][3] += wr2 * v3;
                s1a[nt][3][0] += wr3 * v0; s1a[nt][3][1] += wr3 * v1;
                s1a[nt][3][2] += wr3 * v2; s1a[nt][3][3] += wr3 * v3;
            }
        }
    }

    // final: store s1 (bf16)
    #pragma unroll
    for (int nt = 0; nt < 4; ++nt) {
        int tt = wv * 4 + nt;
        int pos = L0 + tt * 256 + 16 * ln15 + 4 * lkb;
        #pragma unroll
        for (int c = 0; c < 4; ++c) {
            ushort4 st; bf16 h;
            h = f2b(s1a[nt][c][0]); st.x = *(unsigned short*)&h;
            h = f2b(s1a[nt][c][1]); st.y = *(unsigned short*)&h;
            h = f2b(s1a[nt][c][2]); st.z = *(unsigned short*)&h;
            h = f2b(s1a[nt][c][3]); st.w = *(unsigned short*)&h;
            *(ushort4*)(&s1[((size_t)bl * 4 + c) * LEN + pos]) = st;
        }
    }
}

// ============ prep: fft-conv A-fragments ============
__global__ __launch_bounds__(256) void k_prep_fft(const float* __restrict__ w_fft,
                                                  short* __restrict__ fragA) {
    int idx = blockIdx.x * 256 + threadIdx.x;
    if (idx >= 4 * 7 * 4 * 2 * 64 * 8) return;
    int i = idx & 7;
    int lane = (idx >> 3) & 63;
    int rest = idx >> 9;
    int ql = rest & 1; rest >>= 1;
    int Mt = rest & 3; rest >>= 2;
    int qb = rest % 7; int c = rest / 7;
    int dlt = lane & 15, kb = lane >> 4;
    int kkp = 32 * (qb * 2 + ql) + 8 * kb + i;
    int kk = kkp - dlt;
    float v = (kk >= 0 && kk < 401) ? w_fft[(Mt * 4 + c) * 401 + kk] : 0.f;
    bf16 h = f2b(v);
    fragA[idx] = *(short*)&h;
}

// ============ Kernel 2: fft conv (4->4, K=401, pad 200) via bf16 MFMA ============
#define FFT_BLKS 568
__global__ __launch_bounds__(256) void k_fft(const short* __restrict__ s1,
        const short* __restrict__ fragA, const float* __restrict__ b_fft,
        bf16* __restrict__ s2) {
    __shared__ __align__(16) short bwin[4][FFT_BLKS * 8];   // 36,352 B
    const int tid = threadIdx.x;
    const int lane = tid & 63, wv = tid >> 6;
    const int wg = blockIdx.x, bl = blockIdx.y;
    const int P0 = wg * 4096;
    const int win0 = P0 - 200;
    const int ln15 = lane & 15, lkb = lane >> 4;

    f32x4 acc[4][4];
    #pragma unroll
    for (int Mt = 0; Mt < 4; ++Mt)
        #pragma unroll
        for (int nt = 0; nt < 4; ++nt)
            acc[Mt][nt] = (f32x4){0.f, 0.f, 0.f, 0.f};

    #pragma unroll 1
    for (int cl = 0; cl < 4; ++cl) {
        const short* src = s1 + ((size_t)bl * 4 + cl) * LEN;
        for (int Lb = tid; Lb < FFT_BLKS; Lb += 256) {
            int gi = win0 + Lb * 8;
            short8 v;
            if (gi >= 0 && gi + 8 <= LEN) {
                v = *(const short8*)(src + gi);
            } else {
                #pragma unroll
                for (int j = 0; j < 8; ++j)
                    v[j] = (gi + j >= 0 && gi + j < LEN) ? src[gi + j] : (short)0;
            }
            int Pb = Lb ^ ((Lb >> 3) & 7);
            *(short8*)(&bwin[cl][Pb * 8]) = v;
        }
    }
    __syncthreads();

    #pragma unroll 1
    for (int cl = 0; cl < 4; ++cl) {
        #pragma unroll 1
        for (int qb = 0; qb < 7; ++qb) {
            short8 af[4][2];
            #pragma unroll
            for (int Mt = 0; Mt < 4; ++Mt)
                #pragma unroll
                for (int ql = 0; ql < 2; ++ql)
                    af[Mt][ql] = *(const short8*)(fragA +
                        (size_t)((((cl * 7 + qb) * 4 + Mt) * 2 + ql) * 64 + lane) * 8);
            #pragma unroll
            for (int nt = 0; nt < 4; ++nt) {
                const int tt = wv * 4 + nt;
                #pragma unroll
                for (int ql = 0; ql < 2; ++ql) {
                    int qc = qb * 2 + ql;
                    int L = 2 * ln15 + lkb + 4 * qc + 32 * tt;
                    int P = L ^ ((L >> 3) & 7);
                    short8 bfr = *(const short8*)(&bwin[cl][P * 8]);
                    #pragma unroll
                    for (int Mt = 0; Mt < 4; ++Mt)
                        acc[Mt][nt] = __builtin_amdgcn_mfma_f32_16x16x32_bf16(
                            af[Mt][ql], bfr, acc[Mt][nt], 0, 0, 0);
                }
            }
        }
    }

    #pragma unroll
    for (int Mt = 0; Mt < 4; ++Mt) {
        float bb = b_fft[Mt];
        #pragma unroll
        for (int nt = 0; nt < 4; ++nt) {
            int tt = wv * 4 + nt;
            int pos = P0 + tt * 256 + 16 * ln15 + 4 * lkb;
            ushort4 st; bf16 h;
            h = f2b(acc[Mt][nt][0] + bb); st.x = *(unsigned short*)&h;
            h = f2b(acc[Mt][nt][1] + bb); st.y = *(unsigned short*)&h;
            h = f2b(acc[Mt][nt][2] + bb); st.z = *(unsigned short*)&h;
            h = f2b(acc[Mt][nt][3] + bb); st.w = *(unsigned short*)&h;
            *(ushort4*)(&s2[((size_t)bl * 4 + Mt) * LEN + pos]) = st;
        }
    }
}

// ============ prep: effect-conv A-fragments ============
__global__ __launch_bounds__(256) void k_prep(const float* __restrict__ w_eff,
                                              short* __restrict__ fragA) {
    int idx = blockIdx.x * 256 + threadIdx.x;
    if (idx >= 40 * 4 * 2 * 5 * 64 * 8) return;
    int i = idx & 7;
    int lane = (idx >> 3) & 63;
    int rest = idx >> 9;
    int ql = rest % 5; rest /= 5;
    int Mt = rest & 1; rest >>= 1;
    int qb = rest & 3; int c = rest >> 2;
    int q = qb * 5 + ql;
    int dlt = lane & 15, kb = lane >> 4;
    int kp = 32 * q + 8 * kb + i;
    int kk = kp - dlt;
    float v = (kk >= 0 && kk < 601) ? w_eff[(Mt * 40 + c) * 601 + kk] : 0.f;
    bf16 h = __float2bfloat16(v);
    fragA[idx] = *(short*)&h;
}

// ============ Kernel 4: effect conv (40->2, K=601) + FUSED gate, partials ============
// Channel split across blockIdx.z (2 halves x 20 ch = 5 chunks), wave-split K.
// Gate: positions outer, channels inner (s2win read/converted once per position).
#define EFF_NBLK 336
#define EFF_SH (EFF_NBLK * 8)      // shorts per channel window
__device__ __forceinline__ void eff_prefetch(const short* __restrict__ mact,
        size_t chanBase, int cc, int tid, int win0, short8 (&yreg)[2][4]) {
    #pragma unroll
    for (int it = 0; it < 2; ++it) {
        int Lb = tid + it * 256;
        if (Lb < EFF_NBLK) {
            int gi = win0 + Lb * 8;
            bool full = (gi + 8 <= LEN);
            #pragma unroll
            for (int ch = 0; ch < 4; ++ch) {
                const short* src = mact + (chanBase + cc * 4 + ch) * (size_t)LEN;
                short8 v = {0, 0, 0, 0, 0, 0, 0, 0};
                if (full) {
                    v = *(const short8*)(src + gi);
                } else {
                    #pragma unroll
                    for (int j = 0; j < 8; ++j)
                        v[j] = (gi + j < LEN) ? src[gi + j] : (short)0;
                }
                yreg[it][ch] = v;
            }
        }
    }
}

__global__ __launch_bounds__(256, 3) void k_effect(const short* __restrict__ mact,
        const short* __restrict__ s2,
        const short* __restrict__ fragA,
        const float* __restrict__ w_expand, const float* __restrict__ b_expand,
        float* __restrict__ part) {
    // carved shared block: bwin | s2win | wexp | bexp ; reduction reuses bwin+s2win
    __shared__ __align__(16) char smem[2 * EFF_SH * 4 * 2 + 160 * 4 + 40 * 4];
    short (*bwin)[EFF_SH]  = (short(*)[EFF_SH])smem;
    short (*s2win)[EFF_SH] = (short(*)[EFF_SH])(smem + EFF_SH * 4 * 2);
    float* wexp = (float*)(smem + 2 * EFF_SH * 4 * 2);
    float* bexp = wexp + 160;
    float* red  = (float*)smem;   // 32 KB scratch, used after cc loop

    const int tid = threadIdx.x;
    const int lane = tid & 63, wv = tid >> 6;
    const int wgl = blockIdx.x, bl = blockIdx.y, half = blockIdx.z;
    const int coff = half * 20;          // channel offset of this half
    const int L0 = wgl * 2048;
    const int win0 = L0 + 200;
    const int ln15 = lane & 15, lkb = lane >> 4;
    const size_t chanBase = (size_t)bl * 40 + coff;

    // stage expand weights + s2 window ONCE (consumed after loop-top barrier)
    if (tid < 160) wexp[tid] = w_expand[tid];
    if (tid < 40) bexp[tid] = b_expand[tid];
    #pragma unroll 1
    for (int c = 0; c < 4; ++c) {
        const short* sp = s2 + ((size_t)bl * 4 + c) * LEN;
        for (int Lb = tid; Lb < EFF_NBLK; Lb += 256) {
            int gi = win0 + Lb * 8;
            short8 v = {0, 0, 0, 0, 0, 0, 0, 0};
            if (gi + 8 <= LEN) {
                v = *(const short8*)(sp + gi);
            } else {
                #pragma unroll
                for (int j = 0; j < 8; ++j)
                    v[j] = (gi + j < LEN) ? sp[gi + j] : (short)0;
            }
            *(short8*)(&s2win[c][Lb * 8]) = v;
        }
    }

    f32x4 acc[2][8];   // [Mt][tt] — this wave's partial (its channel slice)
    #pragma unroll
    for (int Mt = 0; Mt < 2; ++Mt)
        #pragma unroll
        for (int tt = 0; tt < 8; ++tt)
            acc[Mt][tt] = (f32x4){0.f, 0.f, 0.f, 0.f};

    short8 yreg[2][4];
    eff_prefetch(mact, chanBase, 0, tid, win0, yreg);

    #pragma unroll 1
    for (int cc = 0; cc < 5; ++cc) {
        __syncthreads();
        // ---- write phase: positions outer, channels inner (s2v read once) ----
        #pragma unroll
        for (int it = 0; it < 2; ++it) {
            int Lb = tid + it * 256;
            if (Lb < EFF_NBLK) {
                float s2v[4][8];
                #pragma unroll
                for (int c = 0; c < 4; ++c) {
                    short8 sv = *(const short8*)(&s2win[c][Lb * 8]);
                    #pragma unroll
                    for (int j = 0; j < 8; ++j) s2v[c][j] = us2f((unsigned short)sv[j]);
                }
                int P = Lb ^ ((Lb >> 3) & 7);
                #pragma unroll
                for (int ch = 0; ch < 4; ++ch) {
                    int o = coff + cc * 4 + ch;
                    float w0 = wexp[o * 4 + 0], w1 = wexp[o * 4 + 1];
                    float w2 = wexp[o * 4 + 2], w3 = wexp[o * 4 + 3];
                    float be = bexp[o];
                    short8 w;
                    #pragma unroll
                    for (int j = 0; j < 8; ++j) {
                        float sg = be + w0 * s2v[0][j] + w1 * s2v[1][j]
                                      + w2 * s2v[2][j] + w3 * s2v[3][j];
                        float g = __builtin_amdgcn_rcpf(1.f + __expf(-sg));
                        float yv = us2f((unsigned short)yreg[it][ch][j]) * g;
                        bf16 h = f2b(yv);
                        w[j] = *(short*)&h;
                    }
                    *(short8*)(&bwin[ch][P * 8]) = w;
                }
            }
        }
        __syncthreads();
        // ---- T14: issue next chunk's y loads (land during compute) ----
        if (cc < 4) eff_prefetch(mact, chanBase, cc + 1, tid, win0, yreg);
        // ---- compute phase: this wave's channel only (cl = wv) ----
        const int cg = coff + cc * 4 + wv;
        #pragma unroll 1
        for (int qb = 0; qb < 4; ++qb) {
            short8 af[2][5];
            #pragma unroll
            for (int Mt = 0; Mt < 2; ++Mt)
                #pragma unroll
                for (int ql = 0; ql < 5; ++ql)
                    af[Mt][ql] = *(const short8*)(fragA +
                        (size_t)(((((cg * 4 + qb) * 2 + Mt) * 5 + ql) * 64 + lane) * 8));
            #pragma unroll
            for (int tt = 0; tt < 8; ++tt) {
                #pragma unroll
                for (int ql = 0; ql < 5; ++ql) {
                    int q = qb * 5 + ql;
                    int L = 32 * tt + 2 * ln15 + 4 * q + lkb;
                    int P = L ^ ((L >> 3) & 7);
                    short8 bfr = *(const short8*)(&bwin[wv][P * 8]);
                    acc[0][tt] = __builtin_amdgcn_mfma_f32_16x16x32_bf16(
                        af[0][ql], bfr, acc[0][tt], 0, 0, 0);
                    acc[1][tt] = __builtin_amdgcn_mfma_f32_16x16x32_bf16(
                        af[1][ql], bfr, acc[1][tt], 0, 0, 0);
                }
            }
        }
    }

    // ---- cross-wave reduction: acc_total = sum over waves (bwin/s2win dead) ----
    __syncthreads();
    if (wv == 1 || wv == 3) {
        float* p = red + (wv >> 1) * 4096;
        #pragma unroll
        for (int Mt = 0; Mt < 2; ++Mt)
            #pragma unroll
            for (int tt = 0; tt < 8; ++tt)
                *(f32x4*)(p + (Mt * 8 + tt) * 256 + lane * 4) = acc[Mt][tt];
    }
    __syncthreads();
    if (wv == 0 || wv == 2) {
        float* p = red + (wv >> 1) * 4096;
        #pragma unroll
        for (int Mt = 0; Mt < 2; ++Mt)
            #pragma unroll
            for (int tt = 0; tt < 8; ++tt)
                acc[Mt][tt] += *(const f32x4*)(p + (Mt * 8 + tt) * 256 + lane * 4);
    }
    __syncthreads();
    if (wv == 2) {
        #pragma unroll
        for (int Mt = 0; Mt < 2; ++Mt)
            #pragma unroll
            for (int tt = 0; tt < 8; ++tt)
                *(f32x4*)(red + (Mt * 8 + tt) * 256 + lane * 4) = acc[Mt][tt];
    }
    __syncthreads();
    if (wv == 0) {
        // write fp32 partial (no bias/sigmoid) to part[bl][half][Mt][pos]
        #pragma unroll
        for (int Mt = 0; Mt < 2; ++Mt) {
            #pragma unroll
            for (int tt = 0; tt < 8; ++tt) {
                f32x4 a = acc[Mt][tt];
                a += *(const f32x4*)(red + (Mt * 8 + tt) * 256 + lane * 4);
                int pos = L0 + tt * 256 + 16 * ln15 + 4 * lkb;
                float4 st; st.x = a[0]; st.y = a[1]; st.z = a[2]; st.w = a[3];
                *(float4*)(&part[(((size_t)bl * 2 + half) * 2 + Mt) * LEN + pos]) = st;
            }
        }
    }
}

// ============ Kernel 5: combine partials + bias + sigmoid -> out ============
__global__ __launch_bounds__(256) void k_comb(const float* __restrict__ part,
        const float* __restrict__ b_eff, float* __restrict__ out, int b0) {
    const int tid = threadIdx.x;
    const int bl = blockIdx.y, bg = b0 + bl;
    int l4 = (blockIdx.x * 256 + tid) * 4;
    if (l4 >= LOUT) return;
    #pragma unroll
    for (int Mt = 0; Mt < 2; ++Mt) {
        float bb = b_eff[Mt];
        float4 p0 = *(const float4*)(&part[(((size_t)bl * 2 + 0) * 2 + Mt) * LEN + l4]);
        float4 p1 = *(const float4*)(&part[(((size_t)bl * 2 + 1) * 2 + Mt) * LEN + l4]);
        float4 st;
        st.x = __builtin_amdgcn_rcpf(1.f + __expf(-(p0.x + p1.x + bb)));
        st.y = __builtin_amdgcn_rcpf(1.f + __expf(-(p0.y + p1.y + bb)));
        st.z = __builtin_amdgcn_rcpf(1.f + __expf(-(p0.z + p1.z + bb)));
        st.w = __builtin_amdgcn_rcpf(1.f + __expf(-(p0.w + p1.w + bb)));
        *(float4*)(&out[((size_t)bg * 2 + Mt) * LOUT + l4]) = st;
    }
}

extern "C" void kernel_launch(void* const* d_in, const int* in_sizes, int n_in,
                              void* d_out, int out_size, void* d_ws, size_t ws_size,
                              hipStream_t stream) {
    const float* x        = (const float*)d_in[0];
    const float* w_motif  = (const float*)d_in[1];
    const float* b_motif  = (const float*)d_in[2];
    const float* w_reduce = (const float*)d_in[3];
    const float* b_reduce = (const float*)d_in[4];
    const float* w_fft    = (const float*)d_in[5];
    const float* b_fft    = (const float*)d_in[6];
    const float* w_expand = (const float*)d_in[7];
    const float* b_expand = (const float*)d_in[8];
    const float* w_eff    = (const float*)d_in[9];
    const float* b_eff    = (const float*)d_in[10];
    float* out = (float*)d_out;

    const size_t FRAGA_EFF = (size_t)40 * 4 * 2 * 5 * 64 * 8 * 2;  // 1,638,400
    const size_t FRAGA_FFT = (size_t)4 * 7 * 4 * 2 * 64 * 8 * 2;   //   229,376
    const size_t FRAGA_MOT = (size_t)40 * 4 * 3 * 64 * 8 * 2;      //   491,520
    const size_t XB_B      = (size_t)32 * 4 * LEN * 2;             // 16,777,216
    const size_t HEAD = FRAGA_EFF + FRAGA_FFT + FRAGA_MOT + XB_B;

    short* fragA_eff = (short*)d_ws;
    short* fragA_fft = (short*)((char*)d_ws + FRAGA_EFF);
    short* fragA_mot = (short*)((char*)d_ws + FRAGA_EFF + FRAGA_FFT);
    short* xb        = (short*)((char*)d_ws + FRAGA_EFF + FRAGA_FFT + FRAGA_MOT);
    char*  rest      = (char*)d_ws + HEAD;

    const size_t PB_Y = (size_t)40 * LEN * 2;   // y bf16
    const size_t PB_S = (size_t)4 * LEN * 2;    // s1/s2 bf16
    const size_t PERB = PB_Y + 2 * PB_S + (size_t)2 * 2 * LEN * 4;  // + fp32 partials
    size_t avail = (ws_size > HEAD) ? (ws_size - HEAD) : 0;
    int nb = (int)(avail / PERB);
    if (nb > 32) nb = 32;
    if (nb < 1) nb = 1;

    bf16*  y    = (bf16*)rest;
    bf16*  s1   = (bf16*)(rest + PB_Y * (size_t)nb);
    bf16*  s2   = (bf16*)(rest + (PB_Y + PB_S) * (size_t)nb);
    float* part = (float*)(rest + (PB_Y + 2 * PB_S) * (size_t)nb);

    hipLaunchKernelGGL(k_prep,     dim3(3200), dim3(256), 0, stream, w_eff, fragA_eff);
    hipLaunchKernelGGL(k_prep_fft, dim3(448),  dim3(256), 0, stream, w_fft, fragA_fft);
    hipLaunchKernelGGL(k_prep_mot, dim3(960),  dim3(256), 0, stream, w_motif, fragA_mot);
    hipLaunchKernelGGL(k_x2b,      dim3(4096), dim3(256), 0, stream, x, xb,
                       (int)(32 * 4 * LEN / 8));

    for (int b0 = 0; b0 < 32; b0 += nb) {
        int nbb = (32 - b0 < nb) ? (32 - b0) : nb;
        hipLaunchKernelGGL(k_motif_mfma, dim3(16, nbb), dim3(256), 0, stream,
                           xb, fragA_mot, b_motif, w_reduce, b_reduce, y, s1, b0);
        hipLaunchKernelGGL(k_fft, dim3(16, nbb), dim3(256), 0, stream,
                           (const short*)s1, fragA_fft, b_fft, s2);
        hipLaunchKernelGGL(k_effect, dim3(32, nbb, 2), dim3(256), 0, stream,
                           (const short*)y, (const short*)s2, fragA_eff,
                           w_expand, b_expand, part);
        hipLaunchKernelGGL(k_comb, dim3(64, nbb), dim3(256), 0, stream,
                           part, b_eff, out, b0);
    }
}